// Round 1
// baseline (228.655 us; speedup 1.0000x reference)
//
#include <hip/hip_runtime.h>
#include <hip/hip_bf16.h>

#define NUM_HEADS   32
#define NUM_KV_HEADS 8
#define HEAD_DIM    128
#define GQA          4
#define Q_LEN      256
#define MAX_PAGES  128
#define PAGE_SIZE   16
#define SCALE 0.08838834764831845f

typedef __bf16 bf16x8 __attribute__((ext_vector_type(8)));
typedef float  f32x4  __attribute__((ext_vector_type(4)));

union B8 { uint4 u; bf16x8 v; };

__device__ __forceinline__ unsigned f2bf(float x){
    unsigned u = __builtin_bit_cast(unsigned, x);
    return (u + 0x7fffu + ((u >> 16) & 1u)) >> 16;
}
__device__ __forceinline__ unsigned pack2(float lo, float hi){
    return f2bf(lo) | (f2bf(hi) << 16);
}

__global__ __launch_bounds__(256) void pattn_kernel(
    const float* __restrict__ q,
    const float* __restrict__ knew,
    const float* __restrict__ vnew,
    const float* __restrict__ kcache,
    const float* __restrict__ vcache,
    const int*   __restrict__ ptab,
    const int*   __restrict__ ctxlens,
    float*       __restrict__ out)
{
    __shared__ unsigned short klds[64 * 128];    // K chunk [t][d], bf16, XOR-swizzled
    __shared__ unsigned short vtlds[128 * 64];   // V^T chunk [d][t], bf16, XOR-swizzled

    const int stile = blockIdx.x;   // 0..15 : 16-row q tile
    const int kvh   = blockIdx.y;   // 0..7
    const int b     = blockIdx.z;   // 0..7
    const int tid   = threadIdx.x;
    const int w     = tid >> 6;     // wave id = which q-head of the group
    const int lane  = tid & 63;
    const int hh    = lane >> 4;    // 0..3
    const int cq    = lane & 15;    // q column (softmax) / t row (K frag) / d col (V frag)

    const int s0  = stile * 16;
    const int sb  = stile >> 1;              // 32-block index (uniform for whole tile)
    const int NV  = (sb + 1) * 32;           // visible new tokens
    const int ctxlen = ctxlens[b];
    const int nc1 = (ctxlen + 63) >> 6;      // cached 64-chunks
    const int nc2 = (NV + 63) >> 6;          // new-token 64-chunks
    const int nch = nc1 + nc2;

    const int hq = kvh * GQA + w;

    // Q fragments (B-operand): lane holds Q[s0+cq][32c + 8hh + j], pre-scaled
    B8 qf[4];
    {
        const float* qrow = q + (size_t)(b * Q_LEN + s0 + cq) * (NUM_HEADS * HEAD_DIM)
                              + hq * HEAD_DIM;
        #pragma unroll
        for (int c = 0; c < 4; ++c){
            const float4 f0 = *(const float4*)(qrow + c * 32 + 8 * hh);
            const float4 f1 = *(const float4*)(qrow + c * 32 + 8 * hh + 4);
            qf[c].u.x = pack2(f0.x * SCALE, f0.y * SCALE);
            qf[c].u.y = pack2(f0.z * SCALE, f0.w * SCALE);
            qf[c].u.z = pack2(f1.x * SCALE, f1.y * SCALE);
            qf[c].u.w = pack2(f1.z * SCALE, f1.w * SCALE);
        }
    }

    f32x4 acc[8] = {};              // O[q=4hh+r][16dc+cq]
    float mrun = -1e30f, lrun = 0.f;

    const int srow = tid >> 2;      // 0..63 : staged row
    const int seg  = tid & 3;       // quarter-row

    for (int ch = 0; ch < nch; ++ch){
        const bool cachedc = (ch < nc1);
        const int  base = cachedc ? ch * 64 : (ch - nc1) * 64;
        const int  vlim = cachedc ? ctxlen : NV;

        // ---------------- stage K -> klds, V -> vtlds (transposed) ----------------
        {
            const int t = base + srow;
            size_t roff;
            if (cachedc){
                const int page = ptab[b * MAX_PAGES + (t >> 4)];
                roff = ((size_t)(page * PAGE_SIZE + (t & 15)) * NUM_KV_HEADS + kvh) * HEAD_DIM;
            } else {
                roff = ((size_t)(b * Q_LEN + t) * NUM_KV_HEADS + kvh) * HEAD_DIM;
            }
            const float* kr = (cachedc ? kcache : knew) + roff + seg * 32;
            const float* vr = (cachedc ? vcache : vnew) + roff + seg * 32;
            const int swz = (srow & 7) << 4;
            #pragma unroll
            for (int i = 0; i < 4; ++i){
                float4 a  = *(const float4*)(kr + i * 8);
                float4 c4 = *(const float4*)(kr + i * 8 + 4);
                uint4 wv;
                wv.x = pack2(a.x, a.y);  wv.y = pack2(a.z, a.w);
                wv.z = pack2(c4.x, c4.y); wv.w = pack2(c4.z, c4.w);
                const int byte = srow * 256 + ((seg * 64 + i * 16) ^ swz);
                *(uint4*)((char*)klds + byte) = wv;
            }
            #pragma unroll
            for (int i = 0; i < 8; ++i){
                float4 a = *(const float4*)(vr + i * 4);
                #pragma unroll
                for (int j = 0; j < 4; ++j){
                    const int d  = seg * 32 + i * 4 + j;
                    const float vv = (j == 0) ? a.x : (j == 1) ? a.y : (j == 2) ? a.z : a.w;
                    const int byte = d * 128 + ((srow * 2) ^ ((d & 7) << 4));
                    *(unsigned short*)((char*)vtlds + byte) = (unsigned short)f2bf(vv);
                }
            }
        }
        __syncthreads();

        // ---------------- QK^T (swapped): st[tf] = S^T[t][q] ----------------
        f32x4 st[4] = {};
        #pragma unroll
        for (int c = 0; c < 4; ++c){
            #pragma unroll
            for (int tf = 0; tf < 4; ++tf){
                const int trow = tf * 16 + cq;
                const int byte = trow * 256 + ((c * 64 + hh * 16) ^ ((trow & 7) << 4));
                B8 kf; kf.u = *(const uint4*)((const char*)klds + byte);
                st[tf] = __builtin_amdgcn_mfma_f32_16x16x32_bf16(kf.v, qf[c].v, st[tf], 0, 0, 0);
            }
        }

        // ---------------- mask + online softmax (q = cq per lane) ----------------
        float p[4][4];
        float pm = -1e30f;
        #pragma unroll
        for (int tf = 0; tf < 4; ++tf){
            #pragma unroll
            for (int r = 0; r < 4; ++r){
                const int t = base + tf * 16 + hh * 4 + r;
                const float s = (t < vlim) ? st[tf][r] : -1e30f;
                p[tf][r] = s;
                pm = fmaxf(pm, s);
            }
        }
        pm = fmaxf(pm, __shfl_xor(pm, 16));
        pm = fmaxf(pm, __shfl_xor(pm, 32));
        const float mnew  = fmaxf(mrun, pm);
        const float alpha = __expf(mrun - mnew);
        mrun = mnew;
        float rsum = 0.f;
        #pragma unroll
        for (int tf = 0; tf < 4; ++tf){
            #pragma unroll
            for (int r = 0; r < 4; ++r){
                const float e = __expf(p[tf][r] - mnew);
                p[tf][r] = e;
                rsum += e;
            }
        }
        rsum += __shfl_xor(rsum, 16);
        rsum += __shfl_xor(rsum, 32);
        lrun = lrun * alpha + rsum;

        float a4[4];
        #pragma unroll
        for (int r = 0; r < 4; ++r) a4[r] = __shfl(alpha, hh * 20 + r);
        #pragma unroll
        for (int dc = 0; dc < 8; ++dc){
            #pragma unroll
            for (int r = 0; r < 4; ++r) acc[dc][r] *= a4[r];
        }

        // ---------------- P pack + lane transform + PV ----------------
        unsigned pk01[4], pk23[4];
        #pragma unroll
        for (int tf = 0; tf < 4; ++tf){
            pk01[tf] = pack2(p[tf][0], p[tf][1]);
            pk23[tf] = pack2(p[tf][2], p[tf][3]);
        }
        const int sA = ((2 * hh) & 3) * 16 + cq;
        const int sB = ((2 * hh + 1) & 3) * 16 + cq;
        const bool fsel = (hh >> 1);
        #pragma unroll
        for (int kk = 0; kk < 2; ++kk){
            const unsigned w0a = __shfl((int)pk01[2 * kk],     sA);
            const unsigned w0b = __shfl((int)pk01[2 * kk + 1], sA);
            const unsigned w1a = __shfl((int)pk23[2 * kk],     sA);
            const unsigned w1b = __shfl((int)pk23[2 * kk + 1], sA);
            const unsigned w2a = __shfl((int)pk01[2 * kk],     sB);
            const unsigned w2b = __shfl((int)pk01[2 * kk + 1], sB);
            const unsigned w3a = __shfl((int)pk23[2 * kk],     sB);
            const unsigned w3b = __shfl((int)pk23[2 * kk + 1], sB);
            B8 af;
            af.u.x = fsel ? w0b : w0a;
            af.u.y = fsel ? w1b : w1a;
            af.u.z = fsel ? w2b : w2a;
            af.u.w = fsel ? w3b : w3a;
            #pragma unroll
            for (int dc = 0; dc < 8; ++dc){
                const int drow = dc * 16 + cq;
                const int byte = drow * 128 + (((kk * 32 + hh * 8) * 2) ^ ((drow & 7) << 4));
                B8 vf; vf.u = *(const uint4*)((const char*)vtlds + byte);
                acc[dc] = __builtin_amdgcn_mfma_f32_16x16x32_bf16(af.v, vf.v, acc[dc], 0, 0, 0);
            }
        }
        __syncthreads();
    }

    // ---------------- epilogue ----------------
    const float li = 1.0f / lrun;
    float li4[4];
    #pragma unroll
    for (int r = 0; r < 4; ++r) li4[r] = __shfl(li, hh * 20 + r);
    #pragma unroll
    for (int dc = 0; dc < 8; ++dc){
        #pragma unroll
        for (int r = 0; r < 4; ++r){
            const int so = s0 + hh * 4 + r;
            out[(size_t)(b * Q_LEN + so) * (NUM_HEADS * HEAD_DIM) + hq * HEAD_DIM + dc * 16 + cq]
                = acc[dc][r] * li4[r];
        }
    }
}

extern "C" void kernel_launch(void* const* d_in, const int* in_sizes, int n_in,
                              void* d_out, int out_size, void* d_ws, size_t ws_size,
                              hipStream_t stream) {
    const float* q  = (const float*)d_in[0];
    const float* k  = (const float*)d_in[1];
    const float* v  = (const float*)d_in[2];
    const float* kc = (const float*)d_in[3];
    const float* vc = (const float*)d_in[4];
    const int*   pt = (const int*)d_in[5];
    const int*   cl = (const int*)d_in[6];
    float* o = (float*)d_out;
    dim3 grid(16, 8, 8);
    pattn_kernel<<<grid, 256, 0, stream>>>(q, k, v, kc, vc, pt, cl, o);
}

// Round 2
// 225.655 us; speedup vs baseline: 1.0133x; 1.0133x over previous
//
#include <hip/hip_runtime.h>
#include <hip/hip_bf16.h>

#define NUM_HEADS   32
#define NUM_KV_HEADS 8
#define HEAD_DIM    128
#define GQA          4
#define Q_LEN      256
#define MAX_PAGES  128
#define PAGE_SIZE   16
#define SCALE 0.08838834764831845f

typedef __bf16 bf16x8 __attribute__((ext_vector_type(8)));
typedef float  f32x4  __attribute__((ext_vector_type(4)));

union B8 { uint4 u; bf16x8 v; };

__device__ __forceinline__ unsigned f2bf(float x){
    unsigned u = __builtin_bit_cast(unsigned, x);
    return (u + 0x7fffu + ((u >> 16) & 1u)) >> 16;
}
__device__ __forceinline__ unsigned pack2(float lo, float hi){
    return f2bf(lo) | (f2bf(hi) << 16);
}

// V LDS: subtiled for ds_read_b64_tr_b16.
// byte(t,d) = (d>>4)*VSTRIDE + (t>>2)*128 + (t&3)*32 + (d&15)*2
#define VSTRIDE 2080   // 16 subtiles*128B + 32B stagger (write bank spread)

#define TRR(dst, OFF) asm volatile("ds_read_b64_tr_b16 %0, %1 offset:" OFF \
                                   : "=v"(dst) : "v"(trbase))

typedef __attribute__((address_space(3))) unsigned char lds_as3_t;

__global__ __launch_bounds__(256, 4) void pattn_kernel(
    const float* __restrict__ q,
    const float* __restrict__ knew,
    const float* __restrict__ vnew,
    const float* __restrict__ kcache,
    const float* __restrict__ vcache,
    const int*   __restrict__ ptab,
    const int*   __restrict__ ctxlens,
    float*       __restrict__ out)
{
    __shared__ unsigned short klds[64 * 128];       // K chunk [t][d], bf16, XOR-swizzled
    __shared__ unsigned char  vlds[8 * VSTRIDE];    // V chunk, tr-subtiled

    const int stile = blockIdx.x;   // 0..15 : 16-row q tile
    const int kvh   = blockIdx.y;   // 0..7
    const int b     = blockIdx.z;   // 0..7
    const int tid   = threadIdx.x;
    const int w     = tid >> 6;     // wave id = which q-head of the group
    const int lane  = tid & 63;
    const int hh    = lane >> 4;    // 0..3
    const int cq    = lane & 15;    // q column (softmax) / t row (K frag) / d col (V frag)

    const int s0  = stile * 16;
    const int sb  = stile >> 1;              // 32-block index (uniform for whole tile)
    const int NV  = (sb + 1) * 32;           // visible new tokens
    const int ctxlen = ctxlens[b];
    const int nc1 = (ctxlen + 63) >> 6;      // cached 64-chunks
    const int nc2 = (NV + 63) >> 6;          // new-token 64-chunks
    const int nch = nc1 + nc2;

    const int hq = kvh * GQA + w;

    // LDS byte offset of vlds base for tr reads (canonical per-lane addr: base + lane*8)
    const unsigned trbase =
        (unsigned)(unsigned long long)(lds_as3_t*)(&vlds[0]) + (unsigned)(hh * 128 + cq * 8);

    // Q fragments (B-operand): lane holds Q[s0+cq][32c + 8hh + j], pre-scaled
    B8 qf[4];
    {
        const float* qrow = q + (size_t)(b * Q_LEN + s0 + cq) * (NUM_HEADS * HEAD_DIM)
                              + hq * HEAD_DIM;
        #pragma unroll
        for (int c = 0; c < 4; ++c){
            const float4 f0 = *(const float4*)(qrow + c * 32 + 8 * hh);
            const float4 f1 = *(const float4*)(qrow + c * 32 + 8 * hh + 4);
            qf[c].u.x = pack2(f0.x * SCALE, f0.y * SCALE);
            qf[c].u.y = pack2(f0.z * SCALE, f0.w * SCALE);
            qf[c].u.z = pack2(f1.x * SCALE, f1.y * SCALE);
            qf[c].u.w = pack2(f1.z * SCALE, f1.w * SCALE);
        }
    }

    f32x4 acc[8] = {};              // O[q=4hh+r][16dc+cq]
    float mrun = -1e30f, lrun = 0.f;

    const int srow = tid >> 2;      // 0..63 : staged row (token within chunk)
    const int seg  = tid & 3;       // quarter-row (32 floats each)

    for (int ch = 0; ch < nch; ++ch){
        const bool cachedc = (ch < nc1);
        const int  base = cachedc ? ch * 64 : (ch - nc1) * 64;
        const int  vlim = cachedc ? ctxlen : NV;

        // ---------------- stage K -> klds (swizzled), V -> vlds (tr-subtiled) ----------------
        {
            const int t = base + srow;
            size_t roff;
            if (cachedc){
                const int page = ptab[b * MAX_PAGES + (t >> 4)];
                roff = ((size_t)(page * PAGE_SIZE + (t & 15)) * NUM_KV_HEADS + kvh) * HEAD_DIM;
            } else {
                roff = ((size_t)(b * Q_LEN + t) * NUM_KV_HEADS + kvh) * HEAD_DIM;
            }
            const float* kr = (cachedc ? kcache : knew) + roff + seg * 32;
            const float* vr = (cachedc ? vcache : vnew) + roff + seg * 32;
            const int swz = (srow & 7) << 4;
            #pragma unroll
            for (int i = 0; i < 4; ++i){
                float4 a  = *(const float4*)(kr + i * 8);
                float4 c4 = *(const float4*)(kr + i * 8 + 4);
                uint4 wv;
                wv.x = pack2(a.x, a.y);  wv.y = pack2(a.z, a.w);
                wv.z = pack2(c4.x, c4.y); wv.w = pack2(c4.z, c4.w);
                const int byte = srow * 256 + ((seg * 64 + i * 16) ^ swz);
                *(uint4*)((char*)klds + byte) = wv;
            }
            // V: 2 dblocks of 16 d each, row-major subtiled, vectorized b128 writes
            const int vbyte0 = (srow >> 2) * 128 + (srow & 3) * 32;
            #pragma unroll
            for (int db = 0; db < 2; ++db){
                const float4 a0 = *(const float4*)(vr + db * 16 + 0);
                const float4 a1 = *(const float4*)(vr + db * 16 + 4);
                const float4 a2 = *(const float4*)(vr + db * 16 + 8);
                const float4 a3 = *(const float4*)(vr + db * 16 + 12);
                uint4 w0, w1;
                w0.x = pack2(a0.x, a0.y); w0.y = pack2(a0.z, a0.w);
                w0.z = pack2(a1.x, a1.y); w0.w = pack2(a1.z, a1.w);
                w1.x = pack2(a2.x, a2.y); w1.y = pack2(a2.z, a2.w);
                w1.z = pack2(a3.x, a3.y); w1.w = pack2(a3.z, a3.w);
                const int dbk = seg * 2 + db;
                const int byte = dbk * VSTRIDE + vbyte0;
                *(uint4*)((char*)vlds + byte)      = w0;
                *(uint4*)((char*)vlds + byte + 16) = w1;
            }
        }
        __syncthreads();

        // ---------------- QK^T (swapped): st[tf] = S^T[t][q] ----------------
        f32x4 st[4] = {};
        #pragma unroll
        for (int c = 0; c < 4; ++c){
            #pragma unroll
            for (int tf = 0; tf < 4; ++tf){
                const int trow = tf * 16 + cq;
                const int byte = trow * 256 + ((c * 64 + hh * 16) ^ ((trow & 7) << 4));
                B8 kf; kf.u = *(const uint4*)((const char*)klds + byte);
                st[tf] = __builtin_amdgcn_mfma_f32_16x16x32_bf16(kf.v, qf[c].v, st[tf], 0, 0, 0);
            }
        }

        // ---------------- mask + online softmax (q = cq per lane) ----------------
        float p[4][4];
        float pm = -1e30f;
        #pragma unroll
        for (int tf = 0; tf < 4; ++tf){
            #pragma unroll
            for (int r = 0; r < 4; ++r){
                const int t = base + tf * 16 + hh * 4 + r;
                const float s = (t < vlim) ? st[tf][r] : -1e30f;
                p[tf][r] = s;
                pm = fmaxf(pm, s);
            }
        }
        pm = fmaxf(pm, __shfl_xor(pm, 16));
        pm = fmaxf(pm, __shfl_xor(pm, 32));
        const float mnew  = fmaxf(mrun, pm);
        const float alpha = __expf(mrun - mnew);
        mrun = mnew;
        float rsum = 0.f;
        #pragma unroll
        for (int tf = 0; tf < 4; ++tf){
            #pragma unroll
            for (int r = 0; r < 4; ++r){
                const float e = __expf(p[tf][r] - mnew);
                p[tf][r] = e;
                rsum += e;
            }
        }
        rsum += __shfl_xor(rsum, 16);
        rsum += __shfl_xor(rsum, 32);
        lrun = lrun * alpha + rsum;

        float a4[4];
        #pragma unroll
        for (int r = 0; r < 4; ++r) a4[r] = __shfl(alpha, hh * 20 + r);
        #pragma unroll
        for (int dc = 0; dc < 8; ++dc){
            #pragma unroll
            for (int r = 0; r < 4; ++r) acc[dc][r] *= a4[r];
        }

        // ---------------- P pack (lane-local A fragments, zero shuffles) ----------------
        // k-axis mapping: t(kk, 8hh+j) = 32kk + 16*(j>>2) + 4hh + (j&3)
        // => af(kk) = { pk01[2kk], pk23[2kk], pk01[2kk+1], pk23[2kk+1] } from OWN registers,
        //    V stored in plain t order in the tr-subtiled layout.
        unsigned pk01[4], pk23[4];
        #pragma unroll
        for (int tf = 0; tf < 4; ++tf){
            pk01[tf] = pack2(p[tf][0], p[tf][1]);
            pk23[tf] = pack2(p[tf][2], p[tf][3]);
        }
        B8 af0, af1;
        af0.u.x = pk01[0]; af0.u.y = pk23[0]; af0.u.z = pk01[1]; af0.u.w = pk23[1];
        af1.u.x = pk01[2]; af1.u.y = pk23[2]; af1.u.z = pk01[3]; af1.u.w = pk23[3];

        // ---------------- PV via hardware transpose reads ----------------
        // vf(kk,dc) elem j = V[32kk + 16*(j>>2) + 4hh + (j&3)][16dc+cq]
        // read offsets: dc*VSTRIDE + kk*1024 + half*512 (+ trbase = hh*128 + cq*8)
        {
            unsigned long long r0,r1,r2,r3,r4,r5,r6,r7;
            B8 vf;
            // ---- kk=0, dc=0..3 ----
            TRR(r0, "0");     TRR(r1, "512");
            TRR(r2, "2080");  TRR(r3, "2592");
            TRR(r4, "4160");  TRR(r5, "4672");
            TRR(r6, "6240");  TRR(r7, "6752");
            asm volatile("s_waitcnt lgkmcnt(0)" ::: "memory");
            __builtin_amdgcn_sched_barrier(0);
            vf.u.x=(unsigned)r0; vf.u.y=(unsigned)(r0>>32); vf.u.z=(unsigned)r1; vf.u.w=(unsigned)(r1>>32);
            acc[0] = __builtin_amdgcn_mfma_f32_16x16x32_bf16(af0.v, vf.v, acc[0], 0, 0, 0);
            vf.u.x=(unsigned)r2; vf.u.y=(unsigned)(r2>>32); vf.u.z=(unsigned)r3; vf.u.w=(unsigned)(r3>>32);
            acc[1] = __builtin_amdgcn_mfma_f32_16x16x32_bf16(af0.v, vf.v, acc[1], 0, 0, 0);
            vf.u.x=(unsigned)r4; vf.u.y=(unsigned)(r4>>32); vf.u.z=(unsigned)r5; vf.u.w=(unsigned)(r5>>32);
            acc[2] = __builtin_amdgcn_mfma_f32_16x16x32_bf16(af0.v, vf.v, acc[2], 0, 0, 0);
            vf.u.x=(unsigned)r6; vf.u.y=(unsigned)(r6>>32); vf.u.z=(unsigned)r7; vf.u.w=(unsigned)(r7>>32);
            acc[3] = __builtin_amdgcn_mfma_f32_16x16x32_bf16(af0.v, vf.v, acc[3], 0, 0, 0);
            // ---- kk=0, dc=4..7 ----
            TRR(r0, "8320");  TRR(r1, "8832");
            TRR(r2, "10400"); TRR(r3, "10912");
            TRR(r4, "12480"); TRR(r5, "12992");
            TRR(r6, "14560"); TRR(r7, "15072");
            asm volatile("s_waitcnt lgkmcnt(0)" ::: "memory");
            __builtin_amdgcn_sched_barrier(0);
            vf.u.x=(unsigned)r0; vf.u.y=(unsigned)(r0>>32); vf.u.z=(unsigned)r1; vf.u.w=(unsigned)(r1>>32);
            acc[4] = __builtin_amdgcn_mfma_f32_16x16x32_bf16(af0.v, vf.v, acc[4], 0, 0, 0);
            vf.u.x=(unsigned)r2; vf.u.y=(unsigned)(r2>>32); vf.u.z=(unsigned)r3; vf.u.w=(unsigned)(r3>>32);
            acc[5] = __builtin_amdgcn_mfma_f32_16x16x32_bf16(af0.v, vf.v, acc[5], 0, 0, 0);
            vf.u.x=(unsigned)r4; vf.u.y=(unsigned)(r4>>32); vf.u.z=(unsigned)r5; vf.u.w=(unsigned)(r5>>32);
            acc[6] = __builtin_amdgcn_mfma_f32_16x16x32_bf16(af0.v, vf.v, acc[6], 0, 0, 0);
            vf.u.x=(unsigned)r6; vf.u.y=(unsigned)(r6>>32); vf.u.z=(unsigned)r7; vf.u.w=(unsigned)(r7>>32);
            acc[7] = __builtin_amdgcn_mfma_f32_16x16x32_bf16(af0.v, vf.v, acc[7], 0, 0, 0);
            // ---- kk=1, dc=0..3 ----
            TRR(r0, "1024");  TRR(r1, "1536");
            TRR(r2, "3104");  TRR(r3, "3616");
            TRR(r4, "5184");  TRR(r5, "5696");
            TRR(r6, "7264");  TRR(r7, "7776");
            asm volatile("s_waitcnt lgkmcnt(0)" ::: "memory");
            __builtin_amdgcn_sched_barrier(0);
            vf.u.x=(unsigned)r0; vf.u.y=(unsigned)(r0>>32); vf.u.z=(unsigned)r1; vf.u.w=(unsigned)(r1>>32);
            acc[0] = __builtin_amdgcn_mfma_f32_16x16x32_bf16(af1.v, vf.v, acc[0], 0, 0, 0);
            vf.u.x=(unsigned)r2; vf.u.y=(unsigned)(r2>>32); vf.u.z=(unsigned)r3; vf.u.w=(unsigned)(r3>>32);
            acc[1] = __builtin_amdgcn_mfma_f32_16x16x32_bf16(af1.v, vf.v, acc[1], 0, 0, 0);
            vf.u.x=(unsigned)r4; vf.u.y=(unsigned)(r4>>32); vf.u.z=(unsigned)r5; vf.u.w=(unsigned)(r5>>32);
            acc[2] = __builtin_amdgcn_mfma_f32_16x16x32_bf16(af1.v, vf.v, acc[2], 0, 0, 0);
            vf.u.x=(unsigned)r6; vf.u.y=(unsigned)(r6>>32); vf.u.z=(unsigned)r7; vf.u.w=(unsigned)(r7>>32);
            acc[3] = __builtin_amdgcn_mfma_f32_16x16x32_bf16(af1.v, vf.v, acc[3], 0, 0, 0);
            // ---- kk=1, dc=4..7 ----
            TRR(r0, "9344");  TRR(r1, "9856");
            TRR(r2, "11424"); TRR(r3, "11936");
            TRR(r4, "13504"); TRR(r5, "14016");
            TRR(r6, "15584"); TRR(r7, "16096");
            asm volatile("s_waitcnt lgkmcnt(0)" ::: "memory");
            __builtin_amdgcn_sched_barrier(0);
            vf.u.x=(unsigned)r0; vf.u.y=(unsigned)(r0>>32); vf.u.z=(unsigned)r1; vf.u.w=(unsigned)(r1>>32);
            acc[4] = __builtin_amdgcn_mfma_f32_16x16x32_bf16(af1.v, vf.v, acc[4], 0, 0, 0);
            vf.u.x=(unsigned)r2; vf.u.y=(unsigned)(r2>>32); vf.u.z=(unsigned)r3; vf.u.w=(unsigned)(r3>>32);
            acc[5] = __builtin_amdgcn_mfma_f32_16x16x32_bf16(af1.v, vf.v, acc[5], 0, 0, 0);
            vf.u.x=(unsigned)r4; vf.u.y=(unsigned)(r4>>32); vf.u.z=(unsigned)r5; vf.u.w=(unsigned)(r5>>32);
            acc[6] = __builtin_amdgcn_mfma_f32_16x16x32_bf16(af1.v, vf.v, acc[6], 0, 0, 0);
            vf.u.x=(unsigned)r6; vf.u.y=(unsigned)(r6>>32); vf.u.z=(unsigned)r7; vf.u.w=(unsigned)(r7>>32);
            acc[7] = __builtin_amdgcn_mfma_f32_16x16x32_bf16(af1.v, vf.v, acc[7], 0, 0, 0);
        }
        __syncthreads();
    }

    // ---------------- epilogue ----------------
    const float li = 1.0f / lrun;
    float li4[4];
    #pragma unroll
    for (int r = 0; r < 4; ++r) li4[r] = __shfl(li, hh * 20 + r);
    #pragma unroll
    for (int dc = 0; dc < 8; ++dc){
        #pragma unroll
        for (int r = 0; r < 4; ++r){
            const int so = s0 + hh * 4 + r;
            out[(size_t)(b * Q_LEN + so) * (NUM_HEADS * HEAD_DIM) + hq * HEAD_DIM + dc * 16 + cq]
                = acc[dc][r] * li4[r];
        }
    }
}

extern "C" void kernel_launch(void* const* d_in, const int* in_sizes, int n_in,
                              void* d_out, int out_size, void* d_ws, size_t ws_size,
                              hipStream_t stream) {
    const float* q  = (const float*)d_in[0];
    const float* k  = (const float*)d_in[1];
    const float* v  = (const float*)d_in[2];
    const float* kc = (const float*)d_in[3];
    const float* vc = (const float*)d_in[4];
    const int*   pt = (const int*)d_in[5];
    const int*   cl = (const int*)d_in[6];
    float* o = (float*)d_out;
    dim3 grid(16, 8, 8);
    pattn_kernel<<<grid, 256, 0, stream>>>(q, k, v, kc, vc, pt, cl, o);
}

// Round 3
// 171.252 us; speedup vs baseline: 1.3352x; 1.3177x over previous
//
#include <hip/hip_runtime.h>
#include <hip/hip_bf16.h>

#define NUM_HEADS   32
#define NUM_KV_HEADS 8
#define HEAD_DIM    128
#define GQA          4
#define Q_LEN      256
#define MAX_PAGES  128
#define PAGE_SIZE   16
#define SCALE 0.08838834764831845f

typedef __bf16 bf16x8 __attribute__((ext_vector_type(8)));
typedef float  f32x4  __attribute__((ext_vector_type(4)));

union B8 { uint4 u; bf16x8 v; };

__device__ __forceinline__ unsigned f2bf(float x){
    unsigned u = __builtin_bit_cast(unsigned, x);
    return (u + 0x7fffu + ((u >> 16) & 1u)) >> 16;
}
__device__ __forceinline__ unsigned pack2(float lo, float hi){
    return f2bf(lo) | (f2bf(hi) << 16);
}

// V LDS: subtiled for ds_read_b64_tr_b16.
// byte(t,d) = (d>>4)*VSTRIDE + (t>>2)*128 + (t&3)*32 + (d&15)*2
#define VSTRIDE 2080   // 16 subtiles*128B + 32B stagger

#define TRR(dst, OFF) asm volatile("ds_read_b64_tr_b16 %0, %1 offset:" OFF \
                                   : "=v"(dst) : "v"(trbase))

typedef __attribute__((address_space(3))) unsigned char lds_as3_t;

__global__ __launch_bounds__(256, 2) void pattn_kernel(
    const float* __restrict__ q,
    const float* __restrict__ knew,
    const float* __restrict__ vnew,
    const float* __restrict__ kcache,
    const float* __restrict__ vcache,
    const int*   __restrict__ ptab,
    const int*   __restrict__ ctxlens,
    float*       __restrict__ out)
{
    __shared__ unsigned short klds[64 * 128];       // K chunk [t][d], bf16, XOR-swizzled
    __shared__ unsigned char  vlds[8 * VSTRIDE];    // V chunk, tr-subtiled

    const int s32   = blockIdx.x;   // 0..7 : 32-row q block (also the causal 32-block)
    const int kvh   = blockIdx.y;   // 0..7
    const int b     = blockIdx.z;   // 0..7
    const int tid   = threadIdx.x;
    const int w     = tid >> 6;     // wave id = which q-head of the group
    const int lane  = tid & 63;
    const int hh    = lane >> 4;    // 0..3
    const int cq    = lane & 15;    // q column within each 16-row tile

    const int s0  = s32 * 32;
    const int NV  = (s32 + 1) * 32;          // visible new tokens (uniform for both tiles)
    const int ctxlen = ctxlens[b];
    const int nc1 = (ctxlen + 63) >> 6;      // cached 64-chunks
    const int nc2 = (NV + 63) >> 6;          // new-token 64-chunks
    const int nch = nc1 + nc2;

    const int hq = kvh * GQA + w;

    const unsigned trbase =
        (unsigned)(unsigned long long)(lds_as3_t*)(&vlds[0]) + (unsigned)(hh * 128 + cq * 8);

    // Q fragments (B-operand), two 16-row tiles: lane holds Q[s0+16u+cq][32c+8hh+j], pre-scaled
    B8 qf[2][4];
    #pragma unroll
    for (int u = 0; u < 2; ++u){
        const float* qrow = q + (size_t)(b * Q_LEN + s0 + u * 16 + cq) * (NUM_HEADS * HEAD_DIM)
                              + hq * HEAD_DIM;
        #pragma unroll
        for (int c = 0; c < 4; ++c){
            const float4 f0 = *(const float4*)(qrow + c * 32 + 8 * hh);
            const float4 f1 = *(const float4*)(qrow + c * 32 + 8 * hh + 4);
            qf[u][c].u.x = pack2(f0.x * SCALE, f0.y * SCALE);
            qf[u][c].u.y = pack2(f0.z * SCALE, f0.w * SCALE);
            qf[u][c].u.z = pack2(f1.x * SCALE, f1.y * SCALE);
            qf[u][c].u.w = pack2(f1.z * SCALE, f1.w * SCALE);
        }
    }

    f32x4 acc[2][8] = {};           // [tile][dc] : O[q=4hh+r][16dc+cq]
    float mrun[2] = {-1e30f, -1e30f};
    float lrun[2] = {0.f, 0.f};

    const int srow = tid >> 2;      // 0..63 : staged token within chunk
    const int seg  = tid & 3;       // quarter-row (32 floats each)

    for (int ch = 0; ch < nch; ++ch){
        const bool cachedc = (ch < nc1);
        const int  base = cachedc ? ch * 64 : (ch - nc1) * 64;
        const int  vlim = cachedc ? ctxlen : NV;

        // ---------------- stage K -> klds (swizzled), V -> vlds (tr-subtiled) ----------------
        {
            const int t = base + srow;
            size_t roff;
            if (cachedc){
                const int page = ptab[b * MAX_PAGES + (t >> 4)];
                roff = ((size_t)(page * PAGE_SIZE + (t & 15)) * NUM_KV_HEADS + kvh) * HEAD_DIM;
            } else {
                roff = ((size_t)(b * Q_LEN + t) * NUM_KV_HEADS + kvh) * HEAD_DIM;
            }
            const float* kr = (cachedc ? kcache : knew) + roff + seg * 32;
            const float* vr = (cachedc ? vcache : vnew) + roff + seg * 32;
            const int swz = (srow & 7) << 4;
            #pragma unroll
            for (int i = 0; i < 4; ++i){
                float4 a  = *(const float4*)(kr + i * 8);
                float4 c4 = *(const float4*)(kr + i * 8 + 4);
                uint4 wv;
                wv.x = pack2(a.x, a.y);  wv.y = pack2(a.z, a.w);
                wv.z = pack2(c4.x, c4.y); wv.w = pack2(c4.z, c4.w);
                const int byte = srow * 256 + ((seg * 64 + i * 16) ^ swz);
                *(uint4*)((char*)klds + byte) = wv;
            }
            const int vbyte0 = (srow >> 2) * 128 + (srow & 3) * 32;
            #pragma unroll
            for (int db = 0; db < 2; ++db){
                const float4 a0 = *(const float4*)(vr + db * 16 + 0);
                const float4 a1 = *(const float4*)(vr + db * 16 + 4);
                const float4 a2 = *(const float4*)(vr + db * 16 + 8);
                const float4 a3 = *(const float4*)(vr + db * 16 + 12);
                uint4 w0, w1;
                w0.x = pack2(a0.x, a0.y); w0.y = pack2(a0.z, a0.w);
                w0.z = pack2(a1.x, a1.y); w0.w = pack2(a1.z, a1.w);
                w1.x = pack2(a2.x, a2.y); w1.y = pack2(a2.z, a2.w);
                w1.z = pack2(a3.x, a3.y); w1.w = pack2(a3.z, a3.w);
                const int dbk = seg * 2 + db;
                const int byte = dbk * VSTRIDE + vbyte0;
                *(uint4*)((char*)vlds + byte)      = w0;
                *(uint4*)((char*)vlds + byte + 16) = w1;
            }
        }
        __syncthreads();

        // ---------------- QK^T (swapped): st[u][tf] = S^T[t][q], K frag shared by tiles ----------------
        f32x4 st[2][4] = {};
        #pragma unroll
        for (int c = 0; c < 4; ++c){
            #pragma unroll
            for (int tf = 0; tf < 4; ++tf){
                const int trow = tf * 16 + cq;
                const int byte = trow * 256 + ((c * 64 + hh * 16) ^ ((trow & 7) << 4));
                B8 kf; kf.u = *(const uint4*)((const char*)klds + byte);
                st[0][tf] = __builtin_amdgcn_mfma_f32_16x16x32_bf16(kf.v, qf[0][c].v, st[0][tf], 0, 0, 0);
                st[1][tf] = __builtin_amdgcn_mfma_f32_16x16x32_bf16(kf.v, qf[1][c].v, st[1][tf], 0, 0, 0);
            }
        }

        // ---------------- mask + online softmax + P pack, per tile ----------------
        B8 af[2][2];   // [tile][kk] A-fragments (lane-local, zero shuffles)
        #pragma unroll
        for (int u = 0; u < 2; ++u){
            float p[4][4];
            float pm = -1e30f;
            #pragma unroll
            for (int tf = 0; tf < 4; ++tf){
                #pragma unroll
                for (int r = 0; r < 4; ++r){
                    const int t = base + tf * 16 + hh * 4 + r;
                    const float s = (t < vlim) ? st[u][tf][r] : -1e30f;
                    p[tf][r] = s;
                    pm = fmaxf(pm, s);
                }
            }
            pm = fmaxf(pm, __shfl_xor(pm, 16));
            pm = fmaxf(pm, __shfl_xor(pm, 32));
            const float mnew  = fmaxf(mrun[u], pm);
            const float alpha = __expf(mrun[u] - mnew);
            mrun[u] = mnew;
            float rsum = 0.f;
            #pragma unroll
            for (int tf = 0; tf < 4; ++tf){
                #pragma unroll
                for (int r = 0; r < 4; ++r){
                    const float e = __expf(p[tf][r] - mnew);
                    p[tf][r] = e;
                    rsum += e;
                }
            }
            rsum += __shfl_xor(rsum, 16);
            rsum += __shfl_xor(rsum, 32);
            lrun[u] = lrun[u] * alpha + rsum;

            float a4[4];
            #pragma unroll
            for (int r = 0; r < 4; ++r) a4[r] = __shfl(alpha, hh * 20 + r);
            #pragma unroll
            for (int dc = 0; dc < 8; ++dc){
                #pragma unroll
                for (int r = 0; r < 4; ++r) acc[u][dc][r] *= a4[r];
            }

            // k-axis mapping: t(kk, 8hh+j) = 32kk + 16*(j>>2) + 4hh + (j&3)
            unsigned pk01[4], pk23[4];
            #pragma unroll
            for (int tf = 0; tf < 4; ++tf){
                pk01[tf] = pack2(p[tf][0], p[tf][1]);
                pk23[tf] = pack2(p[tf][2], p[tf][3]);
            }
            af[u][0].u.x = pk01[0]; af[u][0].u.y = pk23[0]; af[u][0].u.z = pk01[1]; af[u][0].u.w = pk23[1];
            af[u][1].u.x = pk01[2]; af[u][1].u.y = pk23[2]; af[u][1].u.z = pk01[3]; af[u][1].u.w = pk23[3];
        }

        // ---------------- PV via hardware transpose reads; vf shared by tiles ----------------
        // vf(kk,dc) elem j = V[32kk + 16*(j>>2) + 4hh + (j&3)][16dc+cq]
        // offsets: dc*VSTRIDE + kk*1024 + half*512 (+ trbase)
        {
            unsigned long long r0,r1,r2,r3,r4,r5,r6,r7;
            B8 vf;
            // ---- kk=0, dc=0..3 ----
            TRR(r0, "0");     TRR(r1, "512");
            TRR(r2, "2080");  TRR(r3, "2592");
            TRR(r4, "4160");  TRR(r5, "4672");
            TRR(r6, "6240");  TRR(r7, "6752");
            asm volatile("s_waitcnt lgkmcnt(0)" ::: "memory");
            __builtin_amdgcn_sched_barrier(0);
            vf.u.x=(unsigned)r0; vf.u.y=(unsigned)(r0>>32); vf.u.z=(unsigned)r1; vf.u.w=(unsigned)(r1>>32);
            acc[0][0] = __builtin_amdgcn_mfma_f32_16x16x32_bf16(af[0][0].v, vf.v, acc[0][0], 0, 0, 0);
            acc[1][0] = __builtin_amdgcn_mfma_f32_16x16x32_bf16(af[1][0].v, vf.v, acc[1][0], 0, 0, 0);
            vf.u.x=(unsigned)r2; vf.u.y=(unsigned)(r2>>32); vf.u.z=(unsigned)r3; vf.u.w=(unsigned)(r3>>32);
            acc[0][1] = __builtin_amdgcn_mfma_f32_16x16x32_bf16(af[0][0].v, vf.v, acc[0][1], 0, 0, 0);
            acc[1][1] = __builtin_amdgcn_mfma_f32_16x16x32_bf16(af[1][0].v, vf.v, acc[1][1], 0, 0, 0);
            vf.u.x=(unsigned)r4; vf.u.y=(unsigned)(r4>>32); vf.u.z=(unsigned)r5; vf.u.w=(unsigned)(r5>>32);
            acc[0][2] = __builtin_amdgcn_mfma_f32_16x16x32_bf16(af[0][0].v, vf.v, acc[0][2], 0, 0, 0);
            acc[1][2] = __builtin_amdgcn_mfma_f32_16x16x32_bf16(af[1][0].v, vf.v, acc[1][2], 0, 0, 0);
            vf.u.x=(unsigned)r6; vf.u.y=(unsigned)(r6>>32); vf.u.z=(unsigned)r7; vf.u.w=(unsigned)(r7>>32);
            acc[0][3] = __builtin_amdgcn_mfma_f32_16x16x32_bf16(af[0][0].v, vf.v, acc[0][3], 0, 0, 0);
            acc[1][3] = __builtin_amdgcn_mfma_f32_16x16x32_bf16(af[1][0].v, vf.v, acc[1][3], 0, 0, 0);
            // ---- kk=0, dc=4..7 ----
            TRR(r0, "8320");  TRR(r1, "8832");
            TRR(r2, "10400"); TRR(r3, "10912");
            TRR(r4, "12480"); TRR(r5, "12992");
            TRR(r6, "14560"); TRR(r7, "15072");
            asm volatile("s_waitcnt lgkmcnt(0)" ::: "memory");
            __builtin_amdgcn_sched_barrier(0);
            vf.u.x=(unsigned)r0; vf.u.y=(unsigned)(r0>>32); vf.u.z=(unsigned)r1; vf.u.w=(unsigned)(r1>>32);
            acc[0][4] = __builtin_amdgcn_mfma_f32_16x16x32_bf16(af[0][0].v, vf.v, acc[0][4], 0, 0, 0);
            acc[1][4] = __builtin_amdgcn_mfma_f32_16x16x32_bf16(af[1][0].v, vf.v, acc[1][4], 0, 0, 0);
            vf.u.x=(unsigned)r2; vf.u.y=(unsigned)(r2>>32); vf.u.z=(unsigned)r3; vf.u.w=(unsigned)(r3>>32);
            acc[0][5] = __builtin_amdgcn_mfma_f32_16x16x32_bf16(af[0][0].v, vf.v, acc[0][5], 0, 0, 0);
            acc[1][5] = __builtin_amdgcn_mfma_f32_16x16x32_bf16(af[1][0].v, vf.v, acc[1][5], 0, 0, 0);
            vf.u.x=(unsigned)r4; vf.u.y=(unsigned)(r4>>32); vf.u.z=(unsigned)r5; vf.u.w=(unsigned)(r5>>32);
            acc[0][6] = __builtin_amdgcn_mfma_f32_16x16x32_bf16(af[0][0].v, vf.v, acc[0][6], 0, 0, 0);
            acc[1][6] = __builtin_amdgcn_mfma_f32_16x16x32_bf16(af[1][0].v, vf.v, acc[1][6], 0, 0, 0);
            vf.u.x=(unsigned)r6; vf.u.y=(unsigned)(r6>>32); vf.u.z=(unsigned)r7; vf.u.w=(unsigned)(r7>>32);
            acc[0][7] = __builtin_amdgcn_mfma_f32_16x16x32_bf16(af[0][0].v, vf.v, acc[0][7], 0, 0, 0);
            acc[1][7] = __builtin_amdgcn_mfma_f32_16x16x32_bf16(af[1][0].v, vf.v, acc[1][7], 0, 0, 0);
            // ---- kk=1, dc=0..3 ----
            TRR(r0, "1024");  TRR(r1, "1536");
            TRR(r2, "3104");  TRR(r3, "3616");
            TRR(r4, "5184");  TRR(r5, "5696");
            TRR(r6, "7264");  TRR(r7, "7776");
            asm volatile("s_waitcnt lgkmcnt(0)" ::: "memory");
            __builtin_amdgcn_sched_barrier(0);
            vf.u.x=(unsigned)r0; vf.u.y=(unsigned)(r0>>32); vf.u.z=(unsigned)r1; vf.u.w=(unsigned)(r1>>32);
            acc[0][0] = __builtin_amdgcn_mfma_f32_16x16x32_bf16(af[0][1].v, vf.v, acc[0][0], 0, 0, 0);
            acc[1][0] = __builtin_amdgcn_mfma_f32_16x16x32_bf16(af[1][1].v, vf.v, acc[1][0], 0, 0, 0);
            vf.u.x=(unsigned)r2; vf.u.y=(unsigned)(r2>>32); vf.u.z=(unsigned)r3; vf.u.w=(unsigned)(r3>>32);
            acc[0][1] = __builtin_amdgcn_mfma_f32_16x16x32_bf16(af[0][1].v, vf.v, acc[0][1], 0, 0, 0);
            acc[1][1] = __builtin_amdgcn_mfma_f32_16x16x32_bf16(af[1][1].v, vf.v, acc[1][1], 0, 0, 0);
            vf.u.x=(unsigned)r4; vf.u.y=(unsigned)(r4>>32); vf.u.z=(unsigned)r5; vf.u.w=(unsigned)(r5>>32);
            acc[0][2] = __builtin_amdgcn_mfma_f32_16x16x32_bf16(af[0][1].v, vf.v, acc[0][2], 0, 0, 0);
            acc[1][2] = __builtin_amdgcn_mfma_f32_16x16x32_bf16(af[1][1].v, vf.v, acc[1][2], 0, 0, 0);
            vf.u.x=(unsigned)r6; vf.u.y=(unsigned)(r6>>32); vf.u.z=(unsigned)r7; vf.u.w=(unsigned)(r7>>32);
            acc[0][3] = __builtin_amdgcn_mfma_f32_16x16x32_bf16(af[0][1].v, vf.v, acc[0][3], 0, 0, 0);
            acc[1][3] = __builtin_amdgcn_mfma_f32_16x16x32_bf16(af[1][1].v, vf.v, acc[1][3], 0, 0, 0);
            // ---- kk=1, dc=4..7 ----
            TRR(r0, "9344");  TRR(r1, "9856");
            TRR(r2, "11424"); TRR(r3, "11936");
            TRR(r4, "13504"); TRR(r5, "14016");
            TRR(r6, "15584"); TRR(r7, "16096");
            asm volatile("s_waitcnt lgkmcnt(0)" ::: "memory");
            __builtin_amdgcn_sched_barrier(0);
            vf.u.x=(unsigned)r0; vf.u.y=(unsigned)(r0>>32); vf.u.z=(unsigned)r1; vf.u.w=(unsigned)(r1>>32);
            acc[0][4] = __builtin_amdgcn_mfma_f32_16x16x32_bf16(af[0][1].v, vf.v, acc[0][4], 0, 0, 0);
            acc[1][4] = __builtin_amdgcn_mfma_f32_16x16x32_bf16(af[1][1].v, vf.v, acc[1][4], 0, 0, 0);
            vf.u.x=(unsigned)r2; vf.u.y=(unsigned)(r2>>32); vf.u.z=(unsigned)r3; vf.u.w=(unsigned)(r3>>32);
            acc[0][5] = __builtin_amdgcn_mfma_f32_16x16x32_bf16(af[0][1].v, vf.v, acc[0][5], 0, 0, 0);
            acc[1][5] = __builtin_amdgcn_mfma_f32_16x16x32_bf16(af[1][1].v, vf.v, acc[1][5], 0, 0, 0);
            vf.u.x=(unsigned)r4; vf.u.y=(unsigned)(r4>>32); vf.u.z=(unsigned)r5; vf.u.w=(unsigned)(r5>>32);
            acc[0][6] = __builtin_amdgcn_mfma_f32_16x16x32_bf16(af[0][1].v, vf.v, acc[0][6], 0, 0, 0);
            acc[1][6] = __builtin_amdgcn_mfma_f32_16x16x32_bf16(af[1][1].v, vf.v, acc[1][6], 0, 0, 0);
            vf.u.x=(unsigned)r6; vf.u.y=(unsigned)(r6>>32); vf.u.z=(unsigned)r7; vf.u.w=(unsigned)(r7>>32);
            acc[0][7] = __builtin_amdgcn_mfma_f32_16x16x32_bf16(af[0][1].v, vf.v, acc[0][7], 0, 0, 0);
            acc[1][7] = __builtin_amdgcn_mfma_f32_16x16x32_bf16(af[1][1].v, vf.v, acc[1][7], 0, 0, 0);
        }
        __syncthreads();
    }

    // ---------------- epilogue ----------------
    #pragma unroll
    for (int u = 0; u < 2; ++u){
        const float li = 1.0f / lrun[u];
        float li4[4];
        #pragma unroll
        for (int r = 0; r < 4; ++r) li4[r] = __shfl(li, hh * 20 + r);
        #pragma unroll
        for (int dc = 0; dc < 8; ++dc){
            #pragma unroll
            for (int r = 0; r < 4; ++r){
                const int so = s0 + u * 16 + hh * 4 + r;
                out[(size_t)(b * Q_LEN + so) * (NUM_HEADS * HEAD_DIM) + hq * HEAD_DIM + dc * 16 + cq]
                    = acc[u][dc][r] * li4[r];
            }
        }
    }
}

extern "C" void kernel_launch(void* const* d_in, const int* in_sizes, int n_in,
                              void* d_out, int out_size, void* d_ws, size_t ws_size,
                              hipStream_t stream) {
    const float* q  = (const float*)d_in[0];
    const float* k  = (const float*)d_in[1];
    const float* v  = (const float*)d_in[2];
    const float* kc = (const float*)d_in[3];
    const float* vc = (const float*)d_in[4];
    const int*   pt = (const int*)d_in[5];
    const int*   cl = (const int*)d_in[6];
    float* o = (float*)d_out;
    dim3 grid(8, 8, 8);
    pattn_kernel<<<grid, 256, 0, stream>>>(q, k, v, kc, vc, pt, cl, o);
}

// Round 4
// 146.251 us; speedup vs baseline: 1.5634x; 1.1709x over previous
//
#include <hip/hip_runtime.h>
#include <hip/hip_bf16.h>

#define NUM_HEADS   32
#define NUM_KV_HEADS 8
#define HEAD_DIM    128
#define GQA          4
#define Q_LEN      256
#define MAX_PAGES  128
#define PAGE_SIZE   16
#define SCALE 0.08838834764831845f

#define NCH_MAX   36                      // ceil((2047+256)/64)
#define CHUNK_B   16384                   // 64 tokens * 128 d * 2B (both K and V images)
#define KSTREAM   ((size_t)NCH_MAX * CHUNK_B)   // 589824 B per (b,kvh) stream
#define NITEMS    512

typedef __bf16 bf16x8 __attribute__((ext_vector_type(8)));
typedef float  f32x4  __attribute__((ext_vector_type(4)));

union B8 { uint4 u; bf16x8 v; };

__device__ __forceinline__ unsigned f2bf(float x){
    unsigned u = __builtin_bit_cast(unsigned, x);
    return (u + 0x7fffu + ((u >> 16) & 1u)) >> 16;
}
__device__ __forceinline__ unsigned pack2(float lo, float hi){
    return f2bf(lo) | (f2bf(hi) << 16);
}

typedef __attribute__((address_space(3))) unsigned char lds_as3_t;
typedef const __attribute__((address_space(1))) void gas_v;
typedef __attribute__((address_space(3))) void las_v;

#define GLD16(g, l) __builtin_amdgcn_global_load_lds((gas_v*)(g), (las_v*)(l), 16, 0, 0)

#define TRR(dst, base, OFF) asm volatile("ds_read_b64_tr_b16 %0, %1 offset:" OFF \
                                         : "=v"(dst) : "v"(base))

// ============================ pre-pass: gather + bf16 + pre-swizzle ============================
// K image per chunk: byte = srow*256 + ((col) ^ ((srow&7)<<4))          (64 x 256B)
// V image per chunk: byte = (d>>4)*2048 + ((t&63)>>2)*128 + (t&3)*32 + (d&15)*2
__global__ __launch_bounds__(256) void prep_kernel(
    const float* __restrict__ knew,
    const float* __restrict__ vnew,
    const float* __restrict__ kcache,
    const float* __restrict__ vcache,
    const int*   __restrict__ ptab,
    const int*   __restrict__ ctxlens,
    unsigned char* __restrict__ kimg,
    unsigned char* __restrict__ vimg)
{
    const int ch  = blockIdx.x;
    const int kvh = blockIdx.y;
    const int b   = blockIdx.z;
    const int ctxlen = ctxlens[b];
    const int lim = ctxlen + Q_LEN;
    const int base = ch * 64;
    if (base >= lim) return;

    const int tid  = threadIdx.x;
    const int srow = tid >> 2;
    const int seg  = tid & 3;
    const int t    = base + srow;

    unsigned char* kdst = kimg + (size_t)(b * 8 + kvh) * KSTREAM + (size_t)ch * CHUNK_B;
    unsigned char* vdst = vimg + (size_t)(b * 8 + kvh) * KSTREAM + (size_t)ch * CHUNK_B;
    const int swz    = (srow & 7) << 4;
    const int vbyte0 = (srow >> 2) * 128 + (srow & 3) * 32;

    if (t < lim){
        size_t roff;
        const float *ksrc, *vsrc;
        if (t < ctxlen){
            const int page = ptab[b * MAX_PAGES + (t >> 4)];
            roff = ((size_t)(page * PAGE_SIZE + (t & 15)) * NUM_KV_HEADS + kvh) * HEAD_DIM;
            ksrc = kcache + roff; vsrc = vcache + roff;
        } else {
            roff = ((size_t)(b * Q_LEN + (t - ctxlen)) * NUM_KV_HEADS + kvh) * HEAD_DIM;
            ksrc = knew + roff; vsrc = vnew + roff;
        }
        const float* kr = ksrc + seg * 32;
        const float* vr = vsrc + seg * 32;
        #pragma unroll
        for (int i = 0; i < 4; ++i){
            float4 a  = *(const float4*)(kr + i * 8);
            float4 c4 = *(const float4*)(kr + i * 8 + 4);
            uint4 wv;
            wv.x = pack2(a.x, a.y);  wv.y = pack2(a.z, a.w);
            wv.z = pack2(c4.x, c4.y); wv.w = pack2(c4.z, c4.w);
            *(uint4*)(kdst + srow * 256 + ((seg * 64 + i * 16) ^ swz)) = wv;
        }
        #pragma unroll
        for (int db = 0; db < 2; ++db){
            const float4 a0 = *(const float4*)(vr + db * 16 + 0);
            const float4 a1 = *(const float4*)(vr + db * 16 + 4);
            const float4 a2 = *(const float4*)(vr + db * 16 + 8);
            const float4 a3 = *(const float4*)(vr + db * 16 + 12);
            uint4 w0, w1;
            w0.x = pack2(a0.x, a0.y); w0.y = pack2(a0.z, a0.w);
            w0.z = pack2(a1.x, a1.y); w0.w = pack2(a1.z, a1.w);
            w1.x = pack2(a2.x, a2.y); w1.y = pack2(a2.z, a2.w);
            w1.z = pack2(a3.x, a3.y); w1.w = pack2(a3.z, a3.w);
            const int dbk = seg * 2 + db;
            *(uint4*)(vdst + dbk * 2048 + vbyte0)      = w0;
            *(uint4*)(vdst + dbk * 2048 + vbyte0 + 16) = w1;
        }
    } else {
        // zero-fill chunk tail so masked (P=0) PV never multiplies garbage/NaN
        const uint4 z = {0u, 0u, 0u, 0u};
        #pragma unroll
        for (int i = 0; i < 4; ++i)
            *(uint4*)(kdst + srow * 256 + ((seg * 64 + i * 16) ^ swz)) = z;
        #pragma unroll
        for (int db = 0; db < 2; ++db){
            const int dbk = seg * 2 + db;
            *(uint4*)(vdst + dbk * 2048 + vbyte0)      = z;
            *(uint4*)(vdst + dbk * 2048 + vbyte0 + 16) = z;
        }
    }
}

// ============================ persistent attention kernel ============================
__global__ __launch_bounds__(256, 2) void attn_kernel(
    const float* __restrict__ q,
    const int*   __restrict__ ctxlens,
    float*       __restrict__ out,
    const unsigned char* __restrict__ kimg,
    const unsigned char* __restrict__ vimg,
    int* __restrict__ counter)
{
    // LDS: K dbuf [2][16KB] at 0, V dbuf [2][16KB] at 32768. s_item aliases last 4B
    // of V buf1 (healed by STAGE before any read; read before any overwrite).
    __shared__ __align__(16) unsigned char lds[65536];
    int* s_item_p = (int*)(lds + 65532);

    const int tid  = threadIdx.x;
    const int w    = tid >> 6;
    const int lane = tid & 63;
    const int hh   = lane >> 4;
    const int cq   = lane & 15;

    const unsigned ldsb3 = (unsigned)(unsigned long long)(lds_as3_t*)(&lds[0]);

    for (;;){
        if (tid == 0) *s_item_p = atomicAdd(counter, 1);
        __syncthreads();
        const int it = *s_item_p;
        if (it >= NITEMS) return;

        // long-ish items (large s32) first; b fastest for concurrency mixing
        const int b   = it & 7;
        const int kvh = (it >> 3) & 7;
        const int s32 = 7 - (it >> 6);

        const int s0 = s32 * 32;
        const int ctxlen = ctxlens[b];
        const int vlim = ctxlen + (s32 + 1) * 32;
        const int nch  = (vlim + 63) >> 6;
        const int hq   = kvh * GQA + w;

        const unsigned char* kstream = kimg + (size_t)(b * 8 + kvh) * KSTREAM;
        const unsigned char* vstream = vimg + (size_t)(b * 8 + kvh) * KSTREAM;

        #define STAGE(CH, PB) do { \
            const unsigned char* kg_ = kstream + (size_t)(CH) * CHUNK_B + (w * 4096 + lane * 16); \
            const unsigned char* vg_ = vstream + (size_t)(CH) * CHUNK_B + (w * 4096 + lane * 16); \
            _Pragma("unroll") \
            for (int i_ = 0; i_ < 4; ++i_){ \
                GLD16(kg_ + i_ * 1024, lds + (PB) * CHUNK_B + w * 4096 + i_ * 1024); \
                GLD16(vg_ + i_ * 1024, lds + 32768 + (PB) * CHUNK_B + w * 4096 + i_ * 1024); \
            } \
        } while (0)

        STAGE(0, 0);   // DMA flies under the Q loads

        // Q fragments (B-operand), two 16-row tiles, pre-scaled
        B8 qf[2][4];
        #pragma unroll
        for (int u = 0; u < 2; ++u){
            const float* qrow = q + (size_t)(b * Q_LEN + s0 + u * 16 + cq) * (NUM_HEADS * HEAD_DIM)
                                  + hq * HEAD_DIM;
            #pragma unroll
            for (int c = 0; c < 4; ++c){
                const float4 f0 = *(const float4*)(qrow + c * 32 + 8 * hh);
                const float4 f1 = *(const float4*)(qrow + c * 32 + 8 * hh + 4);
                qf[u][c].u.x = pack2(f0.x * SCALE, f0.y * SCALE);
                qf[u][c].u.y = pack2(f0.z * SCALE, f0.w * SCALE);
                qf[u][c].u.z = pack2(f1.x * SCALE, f1.y * SCALE);
                qf[u][c].u.w = pack2(f1.z * SCALE, f1.w * SCALE);
            }
        }

        f32x4 acc[2][8] = {};
        float mrun[2] = {-1e30f, -1e30f};
        float lrun[2] = {0.f, 0.f};

        __syncthreads();   // buffer 0 ready (implicit vmcnt(0) drain before barrier)

        for (int ch = 0; ch < nch; ++ch){
            const int pb = ch & 1;
            if (ch + 1 < nch) STAGE(ch + 1, pb ^ 1);   // prefetch flies under compute

            const int base = ch * 64;
            const unsigned kldsb = pb * CHUNK_B;

            // ---------------- QK^T (swapped): st[u][tf] = S^T[t][q] ----------------
            f32x4 st[2][4] = {};
            #pragma unroll
            for (int c = 0; c < 4; ++c){
                #pragma unroll
                for (int tf = 0; tf < 4; ++tf){
                    const int trow = tf * 16 + cq;
                    const unsigned byte = kldsb + trow * 256 + ((c * 64 + hh * 16) ^ ((trow & 7) << 4));
                    B8 kf; kf.u = *(const uint4*)(lds + byte);
                    st[0][tf] = __builtin_amdgcn_mfma_f32_16x16x32_bf16(kf.v, qf[0][c].v, st[0][tf], 0, 0, 0);
                    st[1][tf] = __builtin_amdgcn_mfma_f32_16x16x32_bf16(kf.v, qf[1][c].v, st[1][tf], 0, 0, 0);
                }
            }

            // ---------------- mask + online softmax + P pack ----------------
            B8 af[2][2];
            #pragma unroll
            for (int u = 0; u < 2; ++u){
                float p[4][4];
                float pm = -1e30f;
                #pragma unroll
                for (int tf = 0; tf < 4; ++tf){
                    #pragma unroll
                    for (int r = 0; r < 4; ++r){
                        const int t = base + tf * 16 + hh * 4 + r;
                        const float s = (t < vlim) ? st[u][tf][r] : -1e30f;
                        p[tf][r] = s;
                        pm = fmaxf(pm, s);
                    }
                }
                pm = fmaxf(pm, __shfl_xor(pm, 16));
                pm = fmaxf(pm, __shfl_xor(pm, 32));
                const float mnew  = fmaxf(mrun[u], pm);
                const float alpha = __expf(mrun[u] - mnew);
                mrun[u] = mnew;
                float rsum = 0.f;
                #pragma unroll
                for (int tf = 0; tf < 4; ++tf){
                    #pragma unroll
                    for (int r = 0; r < 4; ++r){
                        const float e = __expf(p[tf][r] - mnew);
                        p[tf][r] = e;
                        rsum += e;
                    }
                }
                rsum += __shfl_xor(rsum, 16);
                rsum += __shfl_xor(rsum, 32);
                lrun[u] = lrun[u] * alpha + rsum;

                float a4[4];
                #pragma unroll
                for (int r = 0; r < 4; ++r) a4[r] = __shfl(alpha, hh * 20 + r);
                #pragma unroll
                for (int dc = 0; dc < 8; ++dc){
                    #pragma unroll
                    for (int r = 0; r < 4; ++r) acc[u][dc][r] *= a4[r];
                }

                // k-axis mapping: t(kk, 8hh+j) = 32kk + 16*(j>>2) + 4hh + (j&3)
                unsigned pk01[4], pk23[4];
                #pragma unroll
                for (int tf = 0; tf < 4; ++tf){
                    pk01[tf] = pack2(p[tf][0], p[tf][1]);
                    pk23[tf] = pack2(p[tf][2], p[tf][3]);
                }
                af[u][0].u.x = pk01[0]; af[u][0].u.y = pk23[0]; af[u][0].u.z = pk01[1]; af[u][0].u.w = pk23[1];
                af[u][1].u.x = pk01[2]; af[u][1].u.y = pk23[2]; af[u][1].u.z = pk01[3]; af[u][1].u.w = pk23[3];
            }

            // ---------------- PV via hardware transpose reads; vf shared by tiles ----------------
            // offsets: dc*2048 + kk*1024 + half*512  (+ trb = 32768 + pb*CHUNK_B + hh*128 + cq*8)
            {
                const unsigned trb = ldsb3 + 32768u + (unsigned)(pb * CHUNK_B) + (unsigned)(hh * 128 + cq * 8);
                unsigned long long r0,r1,r2,r3,r4,r5,r6,r7;
                B8 vf;
                // ---- kk=0, dc=0..3 ----
                TRR(r0, trb, "0");     TRR(r1, trb, "512");
                TRR(r2, trb, "2048");  TRR(r3, trb, "2560");
                TRR(r4, trb, "4096");  TRR(r5, trb, "4608");
                TRR(r6, trb, "6144");  TRR(r7, trb, "6656");
                asm volatile("s_waitcnt lgkmcnt(0)" ::: "memory");
                __builtin_amdgcn_sched_barrier(0);
                vf.u.x=(unsigned)r0; vf.u.y=(unsigned)(r0>>32); vf.u.z=(unsigned)r1; vf.u.w=(unsigned)(r1>>32);
                acc[0][0] = __builtin_amdgcn_mfma_f32_16x16x32_bf16(af[0][0].v, vf.v, acc[0][0], 0, 0, 0);
                acc[1][0] = __builtin_amdgcn_mfma_f32_16x16x32_bf16(af[1][0].v, vf.v, acc[1][0], 0, 0, 0);
                vf.u.x=(unsigned)r2; vf.u.y=(unsigned)(r2>>32); vf.u.z=(unsigned)r3; vf.u.w=(unsigned)(r3>>32);
                acc[0][1] = __builtin_amdgcn_mfma_f32_16x16x32_bf16(af[0][0].v, vf.v, acc[0][1], 0, 0, 0);
                acc[1][1] = __builtin_amdgcn_mfma_f32_16x16x32_bf16(af[1][0].v, vf.v, acc[1][1], 0, 0, 0);
                vf.u.x=(unsigned)r4; vf.u.y=(unsigned)(r4>>32); vf.u.z=(unsigned)r5; vf.u.w=(unsigned)(r5>>32);
                acc[0][2] = __builtin_amdgcn_mfma_f32_16x16x32_bf16(af[0][0].v, vf.v, acc[0][2], 0, 0, 0);
                acc[1][2] = __builtin_amdgcn_mfma_f32_16x16x32_bf16(af[1][0].v, vf.v, acc[1][2], 0, 0, 0);
                vf.u.x=(unsigned)r6; vf.u.y=(unsigned)(r6>>32); vf.u.z=(unsigned)r7; vf.u.w=(unsigned)(r7>>32);
                acc[0][3] = __builtin_amdgcn_mfma_f32_16x16x32_bf16(af[0][0].v, vf.v, acc[0][3], 0, 0, 0);
                acc[1][3] = __builtin_amdgcn_mfma_f32_16x16x32_bf16(af[1][0].v, vf.v, acc[1][3], 0, 0, 0);
                // ---- kk=0, dc=4..7 ----
                TRR(r0, trb, "8192");  TRR(r1, trb, "8704");
                TRR(r2, trb, "10240"); TRR(r3, trb, "10752");
                TRR(r4, trb, "12288"); TRR(r5, trb, "12800");
                TRR(r6, trb, "14336"); TRR(r7, trb, "14848");
                asm volatile("s_waitcnt lgkmcnt(0)" ::: "memory");
                __builtin_amdgcn_sched_barrier(0);
                vf.u.x=(unsigned)r0; vf.u.y=(unsigned)(r0>>32); vf.u.z=(unsigned)r1; vf.u.w=(unsigned)(r1>>32);
                acc[0][4] = __builtin_amdgcn_mfma_f32_16x16x32_bf16(af[0][0].v, vf.v, acc[0][4], 0, 0, 0);
                acc[1][4] = __builtin_amdgcn_mfma_f32_16x16x32_bf16(af[1][0].v, vf.v, acc[1][4], 0, 0, 0);
                vf.u.x=(unsigned)r2; vf.u.y=(unsigned)(r2>>32); vf.u.z=(unsigned)r3; vf.u.w=(unsigned)(r3>>32);
                acc[0][5] = __builtin_amdgcn_mfma_f32_16x16x32_bf16(af[0][0].v, vf.v, acc[0][5], 0, 0, 0);
                acc[1][5] = __builtin_amdgcn_mfma_f32_16x16x32_bf16(af[1][0].v, vf.v, acc[1][5], 0, 0, 0);
                vf.u.x=(unsigned)r4; vf.u.y=(unsigned)(r4>>32); vf.u.z=(unsigned)r5; vf.u.w=(unsigned)(r5>>32);
                acc[0][6] = __builtin_amdgcn_mfma_f32_16x16x32_bf16(af[0][0].v, vf.v, acc[0][6], 0, 0, 0);
                acc[1][6] = __builtin_amdgcn_mfma_f32_16x16x32_bf16(af[1][0].v, vf.v, acc[1][6], 0, 0, 0);
                vf.u.x=(unsigned)r6; vf.u.y=(unsigned)(r6>>32); vf.u.z=(unsigned)r7; vf.u.w=(unsigned)(r7>>32);
                acc[0][7] = __builtin_amdgcn_mfma_f32_16x16x32_bf16(af[0][0].v, vf.v, acc[0][7], 0, 0, 0);
                acc[1][7] = __builtin_amdgcn_mfma_f32_16x16x32_bf16(af[1][0].v, vf.v, acc[1][7], 0, 0, 0);
                // ---- kk=1, dc=0..3 ----
                TRR(r0, trb, "1024");  TRR(r1, trb, "1536");
                TRR(r2, trb, "3072");  TRR(r3, trb, "3584");
                TRR(r4, trb, "5120");  TRR(r5, trb, "5632");
                TRR(r6, trb, "7168");  TRR(r7, trb, "7680");
                asm volatile("s_waitcnt lgkmcnt(0)" ::: "memory");
                __builtin_amdgcn_sched_barrier(0);
                vf.u.x=(unsigned)r0; vf.u.y=(unsigned)(r0>>32); vf.u.z=(unsigned)r1; vf.u.w=(unsigned)(r1>>32);
                acc[0][0] = __builtin_amdgcn_mfma_f32_16x16x32_bf16(af[0][1].v, vf.v, acc[0][0], 0, 0, 0);
                acc[1][0] = __builtin_amdgcn_mfma_f32_16x16x32_bf16(af[1][1].v, vf.v, acc[1][0], 0, 0, 0);
                vf.u.x=(unsigned)r2; vf.u.y=(unsigned)(r2>>32); vf.u.z=(unsigned)r3; vf.u.w=(unsigned)(r3>>32);
                acc[0][1] = __builtin_amdgcn_mfma_f32_16x16x32_bf16(af[0][1].v, vf.v, acc[0][1], 0, 0, 0);
                acc[1][1] = __builtin_amdgcn_mfma_f32_16x16x32_bf16(af[1][1].v, vf.v, acc[1][1], 0, 0, 0);
                vf.u.x=(unsigned)r4; vf.u.y=(unsigned)(r4>>32); vf.u.z=(unsigned)r5; vf.u.w=(unsigned)(r5>>32);
                acc[0][2] = __builtin_amdgcn_mfma_f32_16x16x32_bf16(af[0][1].v, vf.v, acc[0][2], 0, 0, 0);
                acc[1][2] = __builtin_amdgcn_mfma_f32_16x16x32_bf16(af[1][1].v, vf.v, acc[1][2], 0, 0, 0);
                vf.u.x=(unsigned)r6; vf.u.y=(unsigned)(r6>>32); vf.u.z=(unsigned)r7; vf.u.w=(unsigned)(r7>>32);
                acc[0][3] = __builtin_amdgcn_mfma_f32_16x16x32_bf16(af[0][1].v, vf.v, acc[0][3], 0, 0, 0);
                acc[1][3] = __builtin_amdgcn_mfma_f32_16x16x32_bf16(af[1][1].v, vf.v, acc[1][3], 0, 0, 0);
                // ---- kk=1, dc=4..7 ----
                TRR(r0, trb, "9216");  TRR(r1, trb, "9728");
                TRR(r2, trb, "11264"); TRR(r3, trb, "11776");
                TRR(r4, trb, "13312"); TRR(r5, trb, "13824");
                TRR(r6, trb, "15360"); TRR(r7, trb, "15872");
                asm volatile("s_waitcnt lgkmcnt(0)" ::: "memory");
                __builtin_amdgcn_sched_barrier(0);
                vf.u.x=(unsigned)r0; vf.u.y=(unsigned)(r0>>32); vf.u.z=(unsigned)r1; vf.u.w=(unsigned)(r1>>32);
                acc[0][4] = __builtin_amdgcn_mfma_f32_16x16x32_bf16(af[0][1].v, vf.v, acc[0][4], 0, 0, 0);
                acc[1][4] = __builtin_amdgcn_mfma_f32_16x16x32_bf16(af[1][1].v, vf.v, acc[1][4], 0, 0, 0);
                vf.u.x=(unsigned)r2; vf.u.y=(unsigned)(r2>>32); vf.u.z=(unsigned)r3; vf.u.w=(unsigned)(r3>>32);
                acc[0][5] = __builtin_amdgcn_mfma_f32_16x16x32_bf16(af[0][1].v, vf.v, acc[0][5], 0, 0, 0);
                acc[1][5] = __builtin_amdgcn_mfma_f32_16x16x32_bf16(af[1][1].v, vf.v, acc[1][5], 0, 0, 0);
                vf.u.x=(unsigned)r4; vf.u.y=(unsigned)(r4>>32); vf.u.z=(unsigned)r5; vf.u.w=(unsigned)(r5>>32);
                acc[0][6] = __builtin_amdgcn_mfma_f32_16x16x32_bf16(af[0][1].v, vf.v, acc[0][6], 0, 0, 0);
                acc[1][6] = __builtin_amdgcn_mfma_f32_16x16x32_bf16(af[1][1].v, vf.v, acc[1][6], 0, 0, 0);
                vf.u.x=(unsigned)r6; vf.u.y=(unsigned)(r6>>32); vf.u.z=(unsigned)r7; vf.u.w=(unsigned)(r7>>32);
                acc[0][7] = __builtin_amdgcn_mfma_f32_16x16x32_bf16(af[0][1].v, vf.v, acc[0][7], 0, 0, 0);
                acc[1][7] = __builtin_amdgcn_mfma_f32_16x16x32_bf16(af[1][1].v, vf.v, acc[1][7], 0, 0, 0);
            }
            __syncthreads();   // drains prefetch DMA (vmcnt) + joins waves: next buffer ready
        }

        // ---------------- epilogue ----------------
        #pragma unroll
        for (int u = 0; u < 2; ++u){
            const float li = 1.0f / lrun[u];
            float li4[4];
            #pragma unroll
            for (int r = 0; r < 4; ++r) li4[r] = __shfl(li, hh * 20 + r);
            #pragma unroll
            for (int dc = 0; dc < 8; ++dc){
                #pragma unroll
                for (int r = 0; r < 4; ++r){
                    const int so = s0 + u * 16 + hh * 4 + r;
                    out[(size_t)(b * Q_LEN + so) * (NUM_HEADS * HEAD_DIM) + hq * HEAD_DIM + dc * 16 + cq]
                        = acc[u][dc][r] * li4[r];
                }
            }
        }
        #undef STAGE
    }
}

// ============================ fallback (round-3 kernel) if ws too small ============================
#define VSTRIDE 2080

__global__ __launch_bounds__(256, 2) void pattn_fallback(
    const float* __restrict__ q,
    const float* __restrict__ knew,
    const float* __restrict__ vnew,
    const float* __restrict__ kcache,
    const float* __restrict__ vcache,
    const int*   __restrict__ ptab,
    const int*   __restrict__ ctxlens,
    float*       __restrict__ out)
{
    __shared__ unsigned short klds[64 * 128];
    __shared__ unsigned char  vlds[8 * VSTRIDE];

    const int s32   = blockIdx.x;
    const int kvh   = blockIdx.y;
    const int b     = blockIdx.z;
    const int tid   = threadIdx.x;
    const int w     = tid >> 6;
    const int lane  = tid & 63;
    const int hh    = lane >> 4;
    const int cq    = lane & 15;

    const int s0  = s32 * 32;
    const int NV  = (s32 + 1) * 32;
    const int ctxlen = ctxlens[b];
    const int nc1 = (ctxlen + 63) >> 6;
    const int nc2 = (NV + 63) >> 6;
    const int nch = nc1 + nc2;
    const int hq = kvh * GQA + w;

    const unsigned trbase =
        (unsigned)(unsigned long long)(lds_as3_t*)(&vlds[0]) + (unsigned)(hh * 128 + cq * 8);

    B8 qf[2][4];
    #pragma unroll
    for (int u = 0; u < 2; ++u){
        const float* qrow = q + (size_t)(b * Q_LEN + s0 + u * 16 + cq) * (NUM_HEADS * HEAD_DIM)
                              + hq * HEAD_DIM;
        #pragma unroll
        for (int c = 0; c < 4; ++c){
            const float4 f0 = *(const float4*)(qrow + c * 32 + 8 * hh);
            const float4 f1 = *(const float4*)(qrow + c * 32 + 8 * hh + 4);
            qf[u][c].u.x = pack2(f0.x * SCALE, f0.y * SCALE);
            qf[u][c].u.y = pack2(f0.z * SCALE, f0.w * SCALE);
            qf[u][c].u.z = pack2(f1.x * SCALE, f1.y * SCALE);
            qf[u][c].u.w = pack2(f1.z * SCALE, f1.w * SCALE);
        }
    }

    f32x4 acc[2][8] = {};
    float mrun[2] = {-1e30f, -1e30f};
    float lrun[2] = {0.f, 0.f};

    const int srow = tid >> 2;
    const int seg  = tid & 3;

    for (int ch = 0; ch < nch; ++ch){
        const bool cachedc = (ch < nc1);
        const int  base = cachedc ? ch * 64 : (ch - nc1) * 64;
        const int  vlim = cachedc ? ctxlen : NV;
        {
            const int t = base + srow;
            size_t roff;
            if (cachedc){
                const int page = ptab[b * MAX_PAGES + (t >> 4)];
                roff = ((size_t)(page * PAGE_SIZE + (t & 15)) * NUM_KV_HEADS + kvh) * HEAD_DIM;
            } else {
                roff = ((size_t)(b * Q_LEN + t) * NUM_KV_HEADS + kvh) * HEAD_DIM;
            }
            const float* kr = (cachedc ? kcache : knew) + roff + seg * 32;
            const float* vr = (cachedc ? vcache : vnew) + roff + seg * 32;
            const int swz = (srow & 7) << 4;
            #pragma unroll
            for (int i = 0; i < 4; ++i){
                float4 a  = *(const float4*)(kr + i * 8);
                float4 c4 = *(const float4*)(kr + i * 8 + 4);
                uint4 wv;
                wv.x = pack2(a.x, a.y);  wv.y = pack2(a.z, a.w);
                wv.z = pack2(c4.x, c4.y); wv.w = pack2(c4.z, c4.w);
                const int byte = srow * 256 + ((seg * 64 + i * 16) ^ swz);
                *(uint4*)((char*)klds + byte) = wv;
            }
            const int vbyte0 = (srow >> 2) * 128 + (srow & 3) * 32;
            #pragma unroll
            for (int db = 0; db < 2; ++db){
                const float4 a0 = *(const float4*)(vr + db * 16 + 0);
                const float4 a1 = *(const float4*)(vr + db * 16 + 4);
                const float4 a2 = *(const float4*)(vr + db * 16 + 8);
                const float4 a3 = *(const float4*)(vr + db * 16 + 12);
                uint4 w0, w1;
                w0.x = pack2(a0.x, a0.y); w0.y = pack2(a0.z, a0.w);
                w0.z = pack2(a1.x, a1.y); w0.w = pack2(a1.z, a1.w);
                w1.x = pack2(a2.x, a2.y); w1.y = pack2(a2.z, a2.w);
                w1.z = pack2(a3.x, a3.y); w1.w = pack2(a3.z, a3.w);
                const int dbk = seg * 2 + db;
                const int byte = dbk * VSTRIDE + vbyte0;
                *(uint4*)((char*)vlds + byte)      = w0;
                *(uint4*)((char*)vlds + byte + 16) = w1;
            }
        }
        __syncthreads();

        f32x4 st[2][4] = {};
        #pragma unroll
        for (int c = 0; c < 4; ++c){
            #pragma unroll
            for (int tf = 0; tf < 4; ++tf){
                const int trow = tf * 16 + cq;
                const int byte = trow * 256 + ((c * 64 + hh * 16) ^ ((trow & 7) << 4));
                B8 kf; kf.u = *(const uint4*)((const char*)klds + byte);
                st[0][tf] = __builtin_amdgcn_mfma_f32_16x16x32_bf16(kf.v, qf[0][c].v, st[0][tf], 0, 0, 0);
                st[1][tf] = __builtin_amdgcn_mfma_f32_16x16x32_bf16(kf.v, qf[1][c].v, st[1][tf], 0, 0, 0);
            }
        }

        B8 af[2][2];
        #pragma unroll
        for (int u = 0; u < 2; ++u){
            float p[4][4];
            float pm = -1e30f;
            #pragma unroll
            for (int tf = 0; tf < 4; ++tf){
                #pragma unroll
                for (int r = 0; r < 4; ++r){
                    const int t = base + tf * 16 + hh * 4 + r;
                    const float s = (t < vlim) ? st[u][tf][r] : -1e30f;
                    p[tf][r] = s;
                    pm = fmaxf(pm, s);
                }
            }
            pm = fmaxf(pm, __shfl_xor(pm, 16));
            pm = fmaxf(pm, __shfl_xor(pm, 32));
            const float mnew  = fmaxf(mrun[u], pm);
            const float alpha = __expf(mrun[u] - mnew);
            mrun[u] = mnew;
            float rsum = 0.f;
            #pragma unroll
            for (int tf = 0; tf < 4; ++tf){
                #pragma unroll
                for (int r = 0; r < 4; ++r){
                    const float e = __expf(p[tf][r] - mnew);
                    p[tf][r] = e;
                    rsum += e;
                }
            }
            rsum += __shfl_xor(rsum, 16);
            rsum += __shfl_xor(rsum, 32);
            lrun[u] = lrun[u] * alpha + rsum;

            float a4[4];
            #pragma unroll
            for (int r = 0; r < 4; ++r) a4[r] = __shfl(alpha, hh * 20 + r);
            #pragma unroll
            for (int dc = 0; dc < 8; ++dc){
                #pragma unroll
                for (int r = 0; r < 4; ++r) acc[u][dc][r] *= a4[r];
            }

            unsigned pk01[4], pk23[4];
            #pragma unroll
            for (int tf = 0; tf < 4; ++tf){
                pk01[tf] = pack2(p[tf][0], p[tf][1]);
                pk23[tf] = pack2(p[tf][2], p[tf][3]);
            }
            af[u][0].u.x = pk01[0]; af[u][0].u.y = pk23[0]; af[u][0].u.z = pk01[1]; af[u][0].u.w = pk23[1];
            af[u][1].u.x = pk01[2]; af[u][1].u.y = pk23[2]; af[u][1].u.z = pk01[3]; af[u][1].u.w = pk23[3];
        }

        {
            unsigned long long r0,r1,r2,r3,r4,r5,r6,r7;
            B8 vf;
            TRR(r0, trbase, "0");     TRR(r1, trbase, "512");
            TRR(r2, trbase, "2080");  TRR(r3, trbase, "2592");
            TRR(r4, trbase, "4160");  TRR(r5, trbase, "4672");
            TRR(r6, trbase, "6240");  TRR(r7, trbase, "6752");
            asm volatile("s_waitcnt lgkmcnt(0)" ::: "memory");
            __builtin_amdgcn_sched_barrier(0);
            vf.u.x=(unsigned)r0; vf.u.y=(unsigned)(r0>>32); vf.u.z=(unsigned)r1; vf.u.w=(unsigned)(r1>>32);
            acc[0][0] = __builtin_amdgcn_mfma_f32_16x16x32_bf16(af[0][0].v, vf.v, acc[0][0], 0, 0, 0);
            acc[1][0] = __builtin_amdgcn_mfma_f32_16x16x32_bf16(af[1][0].v, vf.v, acc[1][0], 0, 0, 0);
            vf.u.x=(unsigned)r2; vf.u.y=(unsigned)(r2>>32); vf.u.z=(unsigned)r3; vf.u.w=(unsigned)(r3>>32);
            acc[0][1] = __builtin_amdgcn_mfma_f32_16x16x32_bf16(af[0][0].v, vf.v, acc[0][1], 0, 0, 0);
            acc[1][1] = __builtin_amdgcn_mfma_f32_16x16x32_bf16(af[1][0].v, vf.v, acc[1][1], 0, 0, 0);
            vf.u.x=(unsigned)r4; vf.u.y=(unsigned)(r4>>32); vf.u.z=(unsigned)r5; vf.u.w=(unsigned)(r5>>32);
            acc[0][2] = __builtin_amdgcn_mfma_f32_16x16x32_bf16(af[0][0].v, vf.v, acc[0][2], 0, 0, 0);
            acc[1][2] = __builtin_amdgcn_mfma_f32_16x16x32_bf16(af[1][0].v, vf.v, acc[1][2], 0, 0, 0);
            vf.u.x=(unsigned)r6; vf.u.y=(unsigned)(r6>>32); vf.u.z=(unsigned)r7; vf.u.w=(unsigned)(r7>>32);
            acc[0][3] = __builtin_amdgcn_mfma_f32_16x16x32_bf16(af[0][0].v, vf.v, acc[0][3], 0, 0, 0);
            acc[1][3] = __builtin_amdgcn_mfma_f32_16x16x32_bf16(af[1][0].v, vf.v, acc[1][3], 0, 0, 0);
            TRR(r0, trbase, "8320");  TRR(r1, trbase, "8832");
            TRR(r2, trbase, "10400"); TRR(r3, trbase, "10912");
            TRR(r4, trbase, "12480"); TRR(r5, trbase, "12992");
            TRR(r6, trbase, "14560"); TRR(r7, trbase, "15072");
            asm volatile("s_waitcnt lgkmcnt(0)" ::: "memory");
            __builtin_amdgcn_sched_barrier(0);
            vf.u.x=(unsigned)r0; vf.u.y=(unsigned)(r0>>32); vf.u.z=(unsigned)r1; vf.u.w=(unsigned)(r1>>32);
            acc[0][4] = __builtin_amdgcn_mfma_f32_16x16x32_bf16(af[0][0].v, vf.v, acc[0][4], 0, 0, 0);
            acc[1][4] = __builtin_amdgcn_mfma_f32_16x16x32_bf16(af[1][0].v, vf.v, acc[1][4], 0, 0, 0);
            vf.u.x=(unsigned)r2; vf.u.y=(unsigned)(r2>>32); vf.u.z=(unsigned)r3; vf.u.w=(unsigned)(r3>>32);
            acc[0][5] = __builtin_amdgcn_mfma_f32_16x16x32_bf16(af[0][0].v, vf.v, acc[0][5], 0, 0, 0);
            acc[1][5] = __builtin_amdgcn_mfma_f32_16x16x32_bf16(af[1][0].v, vf.v, acc[1][5], 0, 0, 0);
            vf.u.x=(unsigned)r4; vf.u.y=(unsigned)(r4>>32); vf.u.z=(unsigned)r5; vf.u.w=(unsigned)(r5>>32);
            acc[0][6] = __builtin_amdgcn_mfma_f32_16x16x32_bf16(af[0][0].v, vf.v, acc[0][6], 0, 0, 0);
            acc[1][6] = __builtin_amdgcn_mfma_f32_16x16x32_bf16(af[1][0].v, vf.v, acc[1][6], 0, 0, 0);
            vf.u.x=(unsigned)r6; vf.u.y=(unsigned)(r6>>32); vf.u.z=(unsigned)r7; vf.u.w=(unsigned)(r7>>32);
            acc[0][7] = __builtin_amdgcn_mfma_f32_16x16x32_bf16(af[0][0].v, vf.v, acc[0][7], 0, 0, 0);
            acc[1][7] = __builtin_amdgcn_mfma_f32_16x16x32_bf16(af[1][0].v, vf.v, acc[1][7], 0, 0, 0);
            TRR(r0, trbase, "1024");  TRR(r1, trbase, "1536");
            TRR(r2, trbase, "3104");  TRR(r3, trbase, "3616");
            TRR(r4, trbase, "5184");  TRR(r5, trbase, "5696");
            TRR(r6, trbase, "7264");  TRR(r7, trbase, "7776");
            asm volatile("s_waitcnt lgkmcnt(0)" ::: "memory");
            __builtin_amdgcn_sched_barrier(0);
            vf.u.x=(unsigned)r0; vf.u.y=(unsigned)(r0>>32); vf.u.z=(unsigned)r1; vf.u.w=(unsigned)(r1>>32);
            acc[0][0] = __builtin_amdgcn_mfma_f32_16x16x32_bf16(af[0][1].v, vf.v, acc[0][0], 0, 0, 0);
            acc[1][0] = __builtin_amdgcn_mfma_f32_16x16x32_bf16(af[1][1].v, vf.v, acc[1][0], 0, 0, 0);
            vf.u.x=(unsigned)r2; vf.u.y=(unsigned)(r2>>32); vf.u.z=(unsigned)r3; vf.u.w=(unsigned)(r3>>32);
            acc[0][1] = __builtin_amdgcn_mfma_f32_16x16x32_bf16(af[0][1].v, vf.v, acc[0][1], 0, 0, 0);
            acc[1][1] = __builtin_amdgcn_mfma_f32_16x16x32_bf16(af[1][1].v, vf.v, acc[1][1], 0, 0, 0);
            vf.u.x=(unsigned)r4; vf.u.y=(unsigned)(r4>>32); vf.u.z=(unsigned)r5; vf.u.w=(unsigned)(r5>>32);
            acc[0][2] = __builtin_amdgcn_mfma_f32_16x16x32_bf16(af[0][1].v, vf.v, acc[0][2], 0, 0, 0);
            acc[1][2] = __builtin_amdgcn_mfma_f32_16x16x32_bf16(af[1][1].v, vf.v, acc[1][2], 0, 0, 0);
            vf.u.x=(unsigned)r6; vf.u.y=(unsigned)(r6>>32); vf.u.z=(unsigned)r7; vf.u.w=(unsigned)(r7>>32);
            acc[0][3] = __builtin_amdgcn_mfma_f32_16x16x32_bf16(af[0][1].v, vf.v, acc[0][3], 0, 0, 0);
            acc[1][3] = __builtin_amdgcn_mfma_f32_16x16x32_bf16(af[1][1].v, vf.v, acc[1][3], 0, 0, 0);
            TRR(r0, trbase, "9344");  TRR(r1, trbase, "9856");
            TRR(r2, trbase, "11424"); TRR(r3, trbase, "11936");
            TRR(r4, trbase, "13504"); TRR(r5, trbase, "14016");
            TRR(r6, trbase, "15584"); TRR(r7, trbase, "16096");
            asm volatile("s_waitcnt lgkmcnt(0)" ::: "memory");
            __builtin_amdgcn_sched_barrier(0);
            vf.u.x=(unsigned)r0; vf.u.y=(unsigned)(r0>>32); vf.u.z=(unsigned)r1; vf.u.w=(unsigned)(r1>>32);
            acc[0][4] = __builtin_amdgcn_mfma_f32_16x16x32_bf16(af[0][1].v, vf.v, acc[0][4], 0, 0, 0);
            acc[1][4] = __builtin_amdgcn_mfma_f32_16x16x32_bf16(af[1][1].v, vf.v, acc[1][4], 0, 0, 0);
            vf.u.x=(unsigned)r2; vf.u.y=(unsigned)(r2>>32); vf.u.z=(unsigned)r3; vf.u.w=(unsigned)(r3>>32);
            acc[0][5] = __builtin_amdgcn_mfma_f32_16x16x32_bf16(af[0][1].v, vf.v, acc[0][5], 0, 0, 0);
            acc[1][5] = __builtin_amdgcn_mfma_f32_16x16x32_bf16(af[1][1].v, vf.v, acc[1][5], 0, 0, 0);
            vf.u.x=(unsigned)r4; vf.u.y=(unsigned)(r4>>32); vf.u.z=(unsigned)r5; vf.u.w=(unsigned)(r5>>32);
            acc[0][6] = __builtin_amdgcn_mfma_f32_16x16x32_bf16(af[0][1].v, vf.v, acc[0][6], 0, 0, 0);
            acc[1][6] = __builtin_amdgcn_mfma_f32_16x16x32_bf16(af[1][1].v, vf.v, acc[1][6], 0, 0, 0);
            vf.u.x=(unsigned)r6; vf.u.y=(unsigned)(r6>>32); vf.u.z=(unsigned)r7; vf.u.w=(unsigned)(r7>>32);
            acc[0][7] = __builtin_amdgcn_mfma_f32_16x16x32_bf16(af[0][1].v, vf.v, acc[0][7], 0, 0, 0);
            acc[1][7] = __builtin_amdgcn_mfma_f32_16x16x32_bf16(af[1][1].v, vf.v, acc[1][7], 0, 0, 0);
        }
        __syncthreads();
    }

    #pragma unroll
    for (int u = 0; u < 2; ++u){
        const float li = 1.0f / lrun[u];
        float li4[4];
        #pragma unroll
        for (int r = 0; r < 4; ++r) li4[r] = __shfl(li, hh * 20 + r);
        #pragma unroll
        for (int dc = 0; dc < 8; ++dc){
            #pragma unroll
            for (int r = 0; r < 4; ++r){
                const int so = s0 + u * 16 + hh * 4 + r;
                out[(size_t)(b * Q_LEN + so) * (NUM_HEADS * HEAD_DIM) + hq * HEAD_DIM + dc * 16 + cq]
                    = acc[u][dc][r] * li4[r];
            }
        }
    }
}

extern "C" void kernel_launch(void* const* d_in, const int* in_sizes, int n_in,
                              void* d_out, int out_size, void* d_ws, size_t ws_size,
                              hipStream_t stream) {
    const float* q  = (const float*)d_in[0];
    const float* k  = (const float*)d_in[1];
    const float* v  = (const float*)d_in[2];
    const float* kc = (const float*)d_in[3];
    const float* vc = (const float*)d_in[4];
    const int*   pt = (const int*)d_in[5];
    const int*   cl = (const int*)d_in[6];
    float* o = (float*)d_out;

    const size_t img_bytes = (size_t)64 * KSTREAM;          // 37,748,736 per image
    const size_t need = 256 + 2 * img_bytes;                // 75,497,728

    if (ws_size >= need) {
        unsigned char* kimg = (unsigned char*)d_ws + 256;
        unsigned char* vimg = kimg + img_bytes;
        hipMemsetAsync(d_ws, 0, 4, stream);                 // work-queue counter
        prep_kernel<<<dim3(NCH_MAX, 8, 8), 256, 0, stream>>>(k, v, kc, vc, pt, cl, kimg, vimg);
        attn_kernel<<<NITEMS, 256, 0, stream>>>(q, cl, o, kimg, vimg, (int*)d_ws);
    } else {
        dim3 grid(8, 8, 8);
        pattn_fallback<<<grid, 256, 0, stream>>>(q, k, v, kc, vc, pt, cl, o);
    }
}

// Round 5
// 134.176 us; speedup vs baseline: 1.7042x; 1.0900x over previous
//
#include <hip/hip_runtime.h>
#include <hip/hip_bf16.h>

#define NUM_HEADS   32
#define NUM_KV_HEADS 8
#define HEAD_DIM    128
#define GQA          4
#define Q_LEN      256
#define MAX_PAGES  128
#define PAGE_SIZE   16
#define SCALE 0.08838834764831845f
#define LOG2E 1.44269504088896340736f
#define RESCALE_THR 8.0f

#define NCH_MAX   36
#define CHUNK_B   16384
#define KSTREAM   ((size_t)NCH_MAX * CHUNK_B)
#define NITEMS    512

typedef __bf16 bf16x8 __attribute__((ext_vector_type(8)));
typedef float  f32x4  __attribute__((ext_vector_type(4)));

union B8 { uint4 u; bf16x8 v; };

__device__ __forceinline__ unsigned f2bf(float x){
    unsigned u = __builtin_bit_cast(unsigned, x);
    return (u + 0x7fffu + ((u >> 16) & 1u)) >> 16;
}
__device__ __forceinline__ unsigned pack2(float lo, float hi){
    return f2bf(lo) | (f2bf(hi) << 16);
}

typedef __attribute__((address_space(3))) unsigned char lds_as3_t;
typedef const __attribute__((address_space(1))) void gas_v;
typedef __attribute__((address_space(3))) void las_v;

#define GLD16(g, l) __builtin_amdgcn_global_load_lds((gas_v*)(g), (las_v*)(l), 16, 0, 0)

#define TRR(dst, base, OFF) asm volatile("ds_read_b64_tr_b16 %0, %1 offset:" OFF \
                                         : "=v"(dst) : "v"(base))

// ============================ pre-pass: gather + bf16 + pre-swizzle ============================
__global__ __launch_bounds__(256) void prep_kernel(
    const float* __restrict__ knew,
    const float* __restrict__ vnew,
    const float* __restrict__ kcache,
    const float* __restrict__ vcache,
    const int*   __restrict__ ptab,
    const int*   __restrict__ ctxlens,
    unsigned char* __restrict__ kimg,
    unsigned char* __restrict__ vimg)
{
    const int ch  = blockIdx.x;
    const int kvh = blockIdx.y;
    const int b   = blockIdx.z;
    const int ctxlen = ctxlens[b];
    const int lim = ctxlen + Q_LEN;
    const int base = ch * 64;
    if (base >= lim) return;

    const int tid  = threadIdx.x;
    const int srow = tid >> 2;
    const int seg  = tid & 3;
    const int t    = base + srow;

    unsigned char* kdst = kimg + (size_t)(b * 8 + kvh) * KSTREAM + (size_t)ch * CHUNK_B;
    unsigned char* vdst = vimg + (size_t)(b * 8 + kvh) * KSTREAM + (size_t)ch * CHUNK_B;
    const int swz    = (srow & 7) << 4;
    const int vbyte0 = (srow >> 2) * 128 + (srow & 3) * 32;

    if (t < lim){
        size_t roff;
        const float *ksrc, *vsrc;
        if (t < ctxlen){
            const int page = ptab[b * MAX_PAGES + (t >> 4)];
            roff = ((size_t)(page * PAGE_SIZE + (t & 15)) * NUM_KV_HEADS + kvh) * HEAD_DIM;
            ksrc = kcache + roff; vsrc = vcache + roff;
        } else {
            roff = ((size_t)(b * Q_LEN + (t - ctxlen)) * NUM_KV_HEADS + kvh) * HEAD_DIM;
            ksrc = knew + roff; vsrc = vnew + roff;
        }
        const float* kr = ksrc + seg * 32;
        const float* vr = vsrc + seg * 32;
        #pragma unroll
        for (int i = 0; i < 4; ++i){
            float4 a  = *(const float4*)(kr + i * 8);
            float4 c4 = *(const float4*)(kr + i * 8 + 4);
            uint4 wv;
            wv.x = pack2(a.x, a.y);  wv.y = pack2(a.z, a.w);
            wv.z = pack2(c4.x, c4.y); wv.w = pack2(c4.z, c4.w);
            *(uint4*)(kdst + srow * 256 + ((seg * 64 + i * 16) ^ swz)) = wv;
        }
        #pragma unroll
        for (int db = 0; db < 2; ++db){
            const float4 a0 = *(const float4*)(vr + db * 16 + 0);
            const float4 a1 = *(const float4*)(vr + db * 16 + 4);
            const float4 a2 = *(const float4*)(vr + db * 16 + 8);
            const float4 a3 = *(const float4*)(vr + db * 16 + 12);
            uint4 w0, w1;
            w0.x = pack2(a0.x, a0.y); w0.y = pack2(a0.z, a0.w);
            w0.z = pack2(a1.x, a1.y); w0.w = pack2(a1.z, a1.w);
            w1.x = pack2(a2.x, a2.y); w1.y = pack2(a2.z, a2.w);
            w1.z = pack2(a3.x, a3.y); w1.w = pack2(a3.z, a3.w);
            const int dbk = seg * 2 + db;
            *(uint4*)(vdst + dbk * 2048 + vbyte0)      = w0;
            *(uint4*)(vdst + dbk * 2048 + vbyte0 + 16) = w1;
        }
    } else {
        const uint4 z = {0u, 0u, 0u, 0u};
        #pragma unroll
        for (int i = 0; i < 4; ++i)
            *(uint4*)(kdst + srow * 256 + ((seg * 64 + i * 16) ^ swz)) = z;
        #pragma unroll
        for (int db = 0; db < 2; ++db){
            const int dbk = seg * 2 + db;
            *(uint4*)(vdst + dbk * 2048 + vbyte0)      = z;
            *(uint4*)(vdst + dbk * 2048 + vbyte0 + 16) = z;
        }
    }
}

// ============================ persistent attention kernel ============================
__global__ __launch_bounds__(256, 2) void attn_kernel(
    const float* __restrict__ q,
    const int*   __restrict__ ctxlens,
    float*       __restrict__ out,
    const unsigned char* __restrict__ kimg,
    const unsigned char* __restrict__ vimg,
    int* __restrict__ counter)
{
    __shared__ __align__(16) unsigned char lds[65536];
    int* s_item_p = (int*)(lds + 65532);

    const int tid  = threadIdx.x;
    const int w    = tid >> 6;
    const int lane = tid & 63;
    const int hh   = lane >> 4;
    const int cq   = lane & 15;

    const unsigned ldsb3 = (unsigned)(unsigned long long)(lds_as3_t*)(&lds[0]);

    for (;;){
        if (tid == 0) *s_item_p = atomicAdd(counter, 1);
        __syncthreads();
        const int it = *s_item_p;
        if (it >= NITEMS) return;

        const int b   = it & 7;
        const int kvh = (it >> 3) & 7;
        const int s32 = 7 - (it >> 6);

        const int s0 = s32 * 32;
        const int ctxlen = ctxlens[b];
        const int vlim = ctxlen + (s32 + 1) * 32;
        const int nch  = (vlim + 63) >> 6;
        const int hq   = kvh * GQA + w;

        const unsigned char* kstream = kimg + (size_t)(b * 8 + kvh) * KSTREAM;
        const unsigned char* vstream = vimg + (size_t)(b * 8 + kvh) * KSTREAM;

        #define STAGE(CH, PB) do { \
            const unsigned char* kg_ = kstream + (size_t)(CH) * CHUNK_B + (w * 4096 + lane * 16); \
            const unsigned char* vg_ = vstream + (size_t)(CH) * CHUNK_B + (w * 4096 + lane * 16); \
            _Pragma("unroll") \
            for (int i_ = 0; i_ < 4; ++i_){ \
                GLD16(kg_ + i_ * 1024, lds + (PB) * CHUNK_B + w * 4096 + i_ * 1024); \
                GLD16(vg_ + i_ * 1024, lds + 32768 + (PB) * CHUNK_B + w * 4096 + i_ * 1024); \
            } \
        } while (0)

        STAGE(0, 0);

        // Q fragments (B-operand), two 16-row tiles, pre-scaled into log2 domain
        B8 qf[2][4];
        #pragma unroll
        for (int u = 0; u < 2; ++u){
            const float* qrow = q + (size_t)(b * Q_LEN + s0 + u * 16 + cq) * (NUM_HEADS * HEAD_DIM)
                                  + hq * HEAD_DIM;
            #pragma unroll
            for (int c = 0; c < 4; ++c){
                const float4 f0 = *(const float4*)(qrow + c * 32 + 8 * hh);
                const float4 f1 = *(const float4*)(qrow + c * 32 + 8 * hh + 4);
                const float sc = SCALE * LOG2E;
                qf[u][c].u.x = pack2(f0.x * sc, f0.y * sc);
                qf[u][c].u.y = pack2(f0.z * sc, f0.w * sc);
                qf[u][c].u.z = pack2(f1.x * sc, f1.y * sc);
                qf[u][c].u.w = pack2(f1.z * sc, f1.w * sc);
            }
        }

        f32x4 acc[2][8] = {};
        float mrun[2] = {-1e30f, -1e30f};
        float lp[2]   = {0.f, 0.f};        // per-lane partial denominator (deferred reduce)

        __syncthreads();

        for (int ch = 0; ch < nch; ++ch){
            const int pb = ch & 1;
            if (ch + 1 < nch) STAGE(ch + 1, pb ^ 1);

            const int base = ch * 64;
            const unsigned kldsb = pb * CHUNK_B;

            // ---------------- QK^T (swapped): st[u][tf] = S^T[t][q] ----------------
            __builtin_amdgcn_s_setprio(1);
            f32x4 st[2][4] = {};
            #pragma unroll
            for (int c = 0; c < 4; ++c){
                #pragma unroll
                for (int tf = 0; tf < 4; ++tf){
                    const int trow = tf * 16 + cq;
                    const unsigned byte = kldsb + trow * 256 + ((c * 64 + hh * 16) ^ ((trow & 7) << 4));
                    B8 kf; kf.u = *(const uint4*)(lds + byte);
                    st[0][tf] = __builtin_amdgcn_mfma_f32_16x16x32_bf16(kf.v, qf[0][c].v, st[0][tf], 0, 0, 0);
                    st[1][tf] = __builtin_amdgcn_mfma_f32_16x16x32_bf16(kf.v, qf[1][c].v, st[1][tf], 0, 0, 0);
                }
            }
            __builtin_amdgcn_s_setprio(0);

            // ---------------- softmax (defer-max + deferred-l, base-2) ----------------
            B8 af[2][2];
            const bool interior = (base + 64 <= vlim);
            #pragma unroll
            for (int u = 0; u < 2; ++u){
                float p[4][4];
                float pm = -1e30f;
                if (interior){
                    #pragma unroll
                    for (int tf = 0; tf < 4; ++tf){
                        #pragma unroll
                        for (int r = 0; r < 4; ++r){
                            const float s = st[u][tf][r];
                            p[tf][r] = s;
                            pm = fmaxf(pm, s);
                        }
                    }
                } else {
                    #pragma unroll
                    for (int tf = 0; tf < 4; ++tf){
                        #pragma unroll
                        for (int r = 0; r < 4; ++r){
                            const int t = base + tf * 16 + hh * 4 + r;
                            const float s = (t < vlim) ? st[u][tf][r] : -1e30f;
                            p[tf][r] = s;
                            pm = fmaxf(pm, s);
                        }
                    }
                }
                pm = fmaxf(pm, __shfl_xor(pm, 16));
                pm = fmaxf(pm, __shfl_xor(pm, 32));

                if (!__all(pm <= mrun[u] + RESCALE_THR)){
                    const float mnew  = fmaxf(mrun[u], pm);
                    const float alpha = __builtin_amdgcn_exp2f(mrun[u] - mnew);
                    mrun[u] = mnew;
                    lp[u] *= alpha;
                    float a4[4];
                    #pragma unroll
                    for (int r = 0; r < 4; ++r) a4[r] = __shfl(alpha, hh * 20 + r);
                    #pragma unroll
                    for (int dc = 0; dc < 8; ++dc){
                        #pragma unroll
                        for (int r = 0; r < 4; ++r) acc[u][dc][r] *= a4[r];
                    }
                }
                const float m = mrun[u];
                float rsum = 0.f;
                #pragma unroll
                for (int tf = 0; tf < 4; ++tf){
                    #pragma unroll
                    for (int r = 0; r < 4; ++r){
                        const float e = __builtin_amdgcn_exp2f(p[tf][r] - m);
                        p[tf][r] = e;
                        rsum += e;
                    }
                }
                lp[u] += rsum;   // per-lane partial only; cross-lane reduce deferred to epilogue

                // k-axis mapping: t(kk, 8hh+j) = 32kk + 16*(j>>2) + 4hh + (j&3)
                unsigned pk01[4], pk23[4];
                #pragma unroll
                for (int tf = 0; tf < 4; ++tf){
                    pk01[tf] = pack2(p[tf][0], p[tf][1]);
                    pk23[tf] = pack2(p[tf][2], p[tf][3]);
                }
                af[u][0].u.x = pk01[0]; af[u][0].u.y = pk23[0]; af[u][0].u.z = pk01[1]; af[u][0].u.w = pk23[1];
                af[u][1].u.x = pk01[2]; af[u][1].u.y = pk23[2]; af[u][1].u.z = pk01[3]; af[u][1].u.w = pk23[3];
            }

            // ---------------- PV via hardware transpose reads; vf shared by tiles ----------------
            {
                const unsigned trb = ldsb3 + 32768u + (unsigned)(pb * CHUNK_B) + (unsigned)(hh * 128 + cq * 8);
                unsigned long long r0,r1,r2,r3,r4,r5,r6,r7;
                B8 vf;
                __builtin_amdgcn_s_setprio(1);
                // ---- kk=0, dc=0..3 ----
                TRR(r0, trb, "0");     TRR(r1, trb, "512");
                TRR(r2, trb, "2048");  TRR(r3, trb, "2560");
                TRR(r4, trb, "4096");  TRR(r5, trb, "4608");
                TRR(r6, trb, "6144");  TRR(r7, trb, "6656");
                asm volatile("s_waitcnt lgkmcnt(0)" ::: "memory");
                __builtin_amdgcn_sched_barrier(0);
                vf.u.x=(unsigned)r0; vf.u.y=(unsigned)(r0>>32); vf.u.z=(unsigned)r1; vf.u.w=(unsigned)(r1>>32);
                acc[0][0] = __builtin_amdgcn_mfma_f32_16x16x32_bf16(af[0][0].v, vf.v, acc[0][0], 0, 0, 0);
                acc[1][0] = __builtin_amdgcn_mfma_f32_16x16x32_bf16(af[1][0].v, vf.v, acc[1][0], 0, 0, 0);
                vf.u.x=(unsigned)r2; vf.u.y=(unsigned)(r2>>32); vf.u.z=(unsigned)r3; vf.u.w=(unsigned)(r3>>32);
                acc[0][1] = __builtin_amdgcn_mfma_f32_16x16x32_bf16(af[0][0].v, vf.v, acc[0][1], 0, 0, 0);
                acc[1][1] = __builtin_amdgcn_mfma_f32_16x16x32_bf16(af[1][0].v, vf.v, acc[1][1], 0, 0, 0);
                vf.u.x=(unsigned)r4; vf.u.y=(unsigned)(r4>>32); vf.u.z=(unsigned)r5; vf.u.w=(unsigned)(r5>>32);
                acc[0][2] = __builtin_amdgcn_mfma_f32_16x16x32_bf16(af[0][0].v, vf.v, acc[0][2], 0, 0, 0);
                acc[1][2] = __builtin_amdgcn_mfma_f32_16x16x32_bf16(af[1][0].v, vf.v, acc[1][2], 0, 0, 0);
                vf.u.x=(unsigned)r6; vf.u.y=(unsigned)(r6>>32); vf.u.z=(unsigned)r7; vf.u.w=(unsigned)(r7>>32);
                acc[0][3] = __builtin_amdgcn_mfma_f32_16x16x32_bf16(af[0][0].v, vf.v, acc[0][3], 0, 0, 0);
                acc[1][3] = __builtin_amdgcn_mfma_f32_16x16x32_bf16(af[1][0].v, vf.v, acc[1][3], 0, 0, 0);
                // ---- kk=0, dc=4..7 ----
                TRR(r0, trb, "8192");  TRR(r1, trb, "8704");
                TRR(r2, trb, "10240"); TRR(r3, trb, "10752");
                TRR(r4, trb, "12288"); TRR(r5, trb, "12800");
                TRR(r6, trb, "14336"); TRR(r7, trb, "14848");
                asm volatile("s_waitcnt lgkmcnt(0)" ::: "memory");
                __builtin_amdgcn_sched_barrier(0);
                vf.u.x=(unsigned)r0; vf.u.y=(unsigned)(r0>>32); vf.u.z=(unsigned)r1; vf.u.w=(unsigned)(r1>>32);
                acc[0][4] = __builtin_amdgcn_mfma_f32_16x16x32_bf16(af[0][0].v, vf.v, acc[0][4], 0, 0, 0);
                acc[1][4] = __builtin_amdgcn_mfma_f32_16x16x32_bf16(af[1][0].v, vf.v, acc[1][4], 0, 0, 0);
                vf.u.x=(unsigned)r2; vf.u.y=(unsigned)(r2>>32); vf.u.z=(unsigned)r3; vf.u.w=(unsigned)(r3>>32);
                acc[0][5] = __builtin_amdgcn_mfma_f32_16x16x32_bf16(af[0][0].v, vf.v, acc[0][5], 0, 0, 0);
                acc[1][5] = __builtin_amdgcn_mfma_f32_16x16x32_bf16(af[1][0].v, vf.v, acc[1][5], 0, 0, 0);
                vf.u.x=(unsigned)r4; vf.u.y=(unsigned)(r4>>32); vf.u.z=(unsigned)r5; vf.u.w=(unsigned)(r5>>32);
                acc[0][6] = __builtin_amdgcn_mfma_f32_16x16x32_bf16(af[0][0].v, vf.v, acc[0][6], 0, 0, 0);
                acc[1][6] = __builtin_amdgcn_mfma_f32_16x16x32_bf16(af[1][0].v, vf.v, acc[1][6], 0, 0, 0);
                vf.u.x=(unsigned)r6; vf.u.y=(unsigned)(r6>>32); vf.u.z=(unsigned)r7; vf.u.w=(unsigned)(r7>>32);
                acc[0][7] = __builtin_amdgcn_mfma_f32_16x16x32_bf16(af[0][0].v, vf.v, acc[0][7], 0, 0, 0);
                acc[1][7] = __builtin_amdgcn_mfma_f32_16x16x32_bf16(af[1][0].v, vf.v, acc[1][7], 0, 0, 0);
                // ---- kk=1, dc=0..3 ----
                TRR(r0, trb, "1024");  TRR(r1, trb, "1536");
                TRR(r2, trb, "3072");  TRR(r3, trb, "3584");
                TRR(r4, trb, "5120");  TRR(r5, trb, "5632");
                TRR(r6, trb, "7168");  TRR(r7, trb, "7680");
                asm volatile("s_waitcnt lgkmcnt(0)" ::: "memory");
                __builtin_amdgcn_sched_barrier(0);
                vf.u.x=(unsigned)r0; vf.u.y=(unsigned)(r0>>32); vf.u.z=(unsigned)r1; vf.u.w=(unsigned)(r1>>32);
                acc[0][0] = __builtin_amdgcn_mfma_f32_16x16x32_bf16(af[0][1].v, vf.v, acc[0][0], 0, 0, 0);
                acc[1][0] = __builtin_amdgcn_mfma_f32_16x16x32_bf16(af[1][1].v, vf.v, acc[1][0], 0, 0, 0);
                vf.u.x=(unsigned)r2; vf.u.y=(unsigned)(r2>>32); vf.u.z=(unsigned)r3; vf.u.w=(unsigned)(r3>>32);
                acc[0][1] = __builtin_amdgcn_mfma_f32_16x16x32_bf16(af[0][1].v, vf.v, acc[0][1], 0, 0, 0);
                acc[1][1] = __builtin_amdgcn_mfma_f32_16x16x32_bf16(af[1][1].v, vf.v, acc[1][1], 0, 0, 0);
                vf.u.x=(unsigned)r4; vf.u.y=(unsigned)(r4>>32); vf.u.z=(unsigned)r5; vf.u.w=(unsigned)(r5>>32);
                acc[0][2] = __builtin_amdgcn_mfma_f32_16x16x32_bf16(af[0][1].v, vf.v, acc[0][2], 0, 0, 0);
                acc[1][2] = __builtin_amdgcn_mfma_f32_16x16x32_bf16(af[1][1].v, vf.v, acc[1][2], 0, 0, 0);
                vf.u.x=(unsigned)r6; vf.u.y=(unsigned)(r6>>32); vf.u.z=(unsigned)r7; vf.u.w=(unsigned)(r7>>32);
                acc[0][3] = __builtin_amdgcn_mfma_f32_16x16x32_bf16(af[0][1].v, vf.v, acc[0][3], 0, 0, 0);
                acc[1][3] = __builtin_amdgcn_mfma_f32_16x16x32_bf16(af[1][1].v, vf.v, acc[1][3], 0, 0, 0);
                // ---- kk=1, dc=4..7 ----
                TRR(r0, trb, "9216");  TRR(r1, trb, "9728");
                TRR(r2, trb, "11264"); TRR(r3, trb, "11776");
                TRR(r4, trb, "13312"); TRR(r5, trb, "13824");
                TRR(r6, trb, "15360"); TRR(r7, trb, "15872");
                asm volatile("s_waitcnt lgkmcnt(0)" ::: "memory");
                __builtin_amdgcn_sched_barrier(0);
                vf.u.x=(unsigned)r0; vf.u.y=(unsigned)(r0>>32); vf.u.z=(unsigned)r1; vf.u.w=(unsigned)(r1>>32);
                acc[0][4] = __builtin_amdgcn_mfma_f32_16x16x32_bf16(af[0][1].v, vf.v, acc[0][4], 0, 0, 0);
                acc[1][4] = __builtin_amdgcn_mfma_f32_16x16x32_bf16(af[1][1].v, vf.v, acc[1][4], 0, 0, 0);
                vf.u.x=(unsigned)r2; vf.u.y=(unsigned)(r2>>32); vf.u.z=(unsigned)r3; vf.u.w=(unsigned)(r3>>32);
                acc[0][5] = __builtin_amdgcn_mfma_f32_16x16x32_bf16(af[0][1].v, vf.v, acc[0][5], 0, 0, 0);
                acc[1][5] = __builtin_amdgcn_mfma_f32_16x16x32_bf16(af[1][1].v, vf.v, acc[1][5], 0, 0, 0);
                vf.u.x=(unsigned)r4; vf.u.y=(unsigned)(r4>>32); vf.u.z=(unsigned)r5; vf.u.w=(unsigned)(r5>>32);
                acc[0][6] = __builtin_amdgcn_mfma_f32_16x16x32_bf16(af[0][1].v, vf.v, acc[0][6], 0, 0, 0);
                acc[1][6] = __builtin_amdgcn_mfma_f32_16x16x32_bf16(af[1][1].v, vf.v, acc[1][6], 0, 0, 0);
                vf.u.x=(unsigned)r6; vf.u.y=(unsigned)(r6>>32); vf.u.z=(unsigned)r7; vf.u.w=(unsigned)(r7>>32);
                acc[0][7] = __builtin_amdgcn_mfma_f32_16x16x32_bf16(af[0][1].v, vf.v, acc[0][7], 0, 0, 0);
                acc[1][7] = __builtin_amdgcn_mfma_f32_16x16x32_bf16(af[1][1].v, vf.v, acc[1][7], 0, 0, 0);
                __builtin_amdgcn_s_setprio(0);
            }
            __syncthreads();
        }

        // ---------------- epilogue: deferred l reduce + normalize ----------------
        #pragma unroll
        for (int u = 0; u < 2; ++u){
            float l = lp[u];
            l += __shfl_xor(l, 16);
            l += __shfl_xor(l, 32);
            const float li = 1.0f / l;
            float li4[4];
            #pragma unroll
            for (int r = 0; r < 4; ++r) li4[r] = __shfl(li, hh * 20 + r);
            #pragma unroll
            for (int dc = 0; dc < 8; ++dc){
                #pragma unroll
                for (int r = 0; r < 4; ++r){
                    const int so = s0 + u * 16 + hh * 4 + r;
                    out[(size_t)(b * Q_LEN + so) * (NUM_HEADS * HEAD_DIM) + hq * HEAD_DIM + dc * 16 + cq]
                        = acc[u][dc][r] * li4[r];
                }
            }
        }
        #undef STAGE
    }
}

// ============================ fallback (round-3 kernel) if ws too small ============================
#define VSTRIDE 2080

__global__ __launch_bounds__(256, 2) void pattn_fallback(
    const float* __restrict__ q,
    const float* __restrict__ knew,
    const float* __restrict__ vnew,
    const float* __restrict__ kcache,
    const float* __restrict__ vcache,
    const int*   __restrict__ ptab,
    const int*   __restrict__ ctxlens,
    float*       __restrict__ out)
{
    __shared__ unsigned short klds[64 * 128];
    __shared__ unsigned char  vlds[8 * VSTRIDE];

    const int s32   = blockIdx.x;
    const int kvh   = blockIdx.y;
    const int b     = blockIdx.z;
    const int tid   = threadIdx.x;
    const int w     = tid >> 6;
    const int lane  = tid & 63;
    const int hh    = lane >> 4;
    const int cq    = lane & 15;

    const int s0  = s32 * 32;
    const int NV  = (s32 + 1) * 32;
    const int ctxlen = ctxlens[b];
    const int nc1 = (ctxlen + 63) >> 6;
    const int nc2 = (NV + 63) >> 6;
    const int nch = nc1 + nc2;
    const int hq = kvh * GQA + w;

    const unsigned trbase =
        (unsigned)(unsigned long long)(lds_as3_t*)(&vlds[0]) + (unsigned)(hh * 128 + cq * 8);

    B8 qf[2][4];
    #pragma unroll
    for (int u = 0; u < 2; ++u){
        const float* qrow = q + (size_t)(b * Q_LEN + s0 + u * 16 + cq) * (NUM_HEADS * HEAD_DIM)
                              + hq * HEAD_DIM;
        #pragma unroll
        for (int c = 0; c < 4; ++c){
            const float4 f0 = *(const float4*)(qrow + c * 32 + 8 * hh);
            const float4 f1 = *(const float4*)(qrow + c * 32 + 8 * hh + 4);
            qf[u][c].u.x = pack2(f0.x * SCALE, f0.y * SCALE);
            qf[u][c].u.y = pack2(f0.z * SCALE, f0.w * SCALE);
            qf[u][c].u.z = pack2(f1.x * SCALE, f1.y * SCALE);
            qf[u][c].u.w = pack2(f1.z * SCALE, f1.w * SCALE);
        }
    }

    f32x4 acc[2][8] = {};
    float mrun[2] = {-1e30f, -1e30f};
    float lrun[2] = {0.f, 0.f};

    const int srow = tid >> 2;
    const int seg  = tid & 3;

    for (int ch = 0; ch < nch; ++ch){
        const bool cachedc = (ch < nc1);
        const int  base = cachedc ? ch * 64 : (ch - nc1) * 64;
        const int  vlim = cachedc ? ctxlen : NV;
        {
            const int t = base + srow;
            size_t roff;
            if (cachedc){
                const int page = ptab[b * MAX_PAGES + (t >> 4)];
                roff = ((size_t)(page * PAGE_SIZE + (t & 15)) * NUM_KV_HEADS + kvh) * HEAD_DIM;
            } else {
                roff = ((size_t)(b * Q_LEN + t) * NUM_KV_HEADS + kvh) * HEAD_DIM;
            }
            const float* kr = (cachedc ? kcache : knew) + roff + seg * 32;
            const float* vr = (cachedc ? vcache : vnew) + roff + seg * 32;
            const int swz = (srow & 7) << 4;
            #pragma unroll
            for (int i = 0; i < 4; ++i){
                float4 a  = *(const float4*)(kr + i * 8);
                float4 c4 = *(const float4*)(kr + i * 8 + 4);
                uint4 wv;
                wv.x = pack2(a.x, a.y);  wv.y = pack2(a.z, a.w);
                wv.z = pack2(c4.x, c4.y); wv.w = pack2(c4.z, c4.w);
                const int byte = srow * 256 + ((seg * 64 + i * 16) ^ swz);
                *(uint4*)((char*)klds + byte) = wv;
            }
            const int vbyte0 = (srow >> 2) * 128 + (srow & 3) * 32;
            #pragma unroll
            for (int db = 0; db < 2; ++db){
                const float4 a0 = *(const float4*)(vr + db * 16 + 0);
                const float4 a1 = *(const float4*)(vr + db * 16 + 4);
                const float4 a2 = *(const float4*)(vr + db * 16 + 8);
                const float4 a3 = *(const float4*)(vr + db * 16 + 12);
                uint4 w0, w1;
                w0.x = pack2(a0.x, a0.y); w0.y = pack2(a0.z, a0.w);
                w0.z = pack2(a1.x, a1.y); w0.w = pack2(a1.z, a1.w);
                w1.x = pack2(a2.x, a2.y); w1.y = pack2(a2.z, a2.w);
                w1.z = pack2(a3.x, a3.y); w1.w = pack2(a3.z, a3.w);
                const int dbk = seg * 2 + db;
                const int byte = dbk * VSTRIDE + vbyte0;
                *(uint4*)((char*)vlds + byte)      = w0;
                *(uint4*)((char*)vlds + byte + 16) = w1;
            }
        }
        __syncthreads();

        f32x4 st[2][4] = {};
        #pragma unroll
        for (int c = 0; c < 4; ++c){
            #pragma unroll
            for (int tf = 0; tf < 4; ++tf){
                const int trow = tf * 16 + cq;
                const int byte = trow * 256 + ((c * 64 + hh * 16) ^ ((trow & 7) << 4));
                B8 kf; kf.u = *(const uint4*)((const char*)klds + byte);
                st[0][tf] = __builtin_amdgcn_mfma_f32_16x16x32_bf16(kf.v, qf[0][c].v, st[0][tf], 0, 0, 0);
                st[1][tf] = __builtin_amdgcn_mfma_f32_16x16x32_bf16(kf.v, qf[1][c].v, st[1][tf], 0, 0, 0);
            }
        }

        B8 af[2][2];
        #pragma unroll
        for (int u = 0; u < 2; ++u){
            float p[4][4];
            float pm = -1e30f;
            #pragma unroll
            for (int tf = 0; tf < 4; ++tf){
                #pragma unroll
                for (int r = 0; r < 4; ++r){
                    const int t = base + tf * 16 + hh * 4 + r;
                    const float s = (t < vlim) ? st[u][tf][r] : -1e30f;
                    p[tf][r] = s;
                    pm = fmaxf(pm, s);
                }
            }
            pm = fmaxf(pm, __shfl_xor(pm, 16));
            pm = fmaxf(pm, __shfl_xor(pm, 32));
            const float mnew  = fmaxf(mrun[u], pm);
            const float alpha = __expf(mrun[u] - mnew);
            mrun[u] = mnew;
            float rsum = 0.f;
            #pragma unroll
            for (int tf = 0; tf < 4; ++tf){
                #pragma unroll
                for (int r = 0; r < 4; ++r){
                    const float e = __expf(p[tf][r] - mnew);
                    p[tf][r] = e;
                    rsum += e;
                }
            }
            rsum += __shfl_xor(rsum, 16);
            rsum += __shfl_xor(rsum, 32);
            lrun[u] = lrun[u] * alpha + rsum;

            float a4[4];
            #pragma unroll
            for (int r = 0; r < 4; ++r) a4[r] = __shfl(alpha, hh * 20 + r);
            #pragma unroll
            for (int dc = 0; dc < 8; ++dc){
                #pragma unroll
                for (int r = 0; r < 4; ++r) acc[u][dc][r] *= a4[r];
            }

            unsigned pk01[4], pk23[4];
            #pragma unroll
            for (int tf = 0; tf < 4; ++tf){
                pk01[tf] = pack2(p[tf][0], p[tf][1]);
                pk23[tf] = pack2(p[tf][2], p[tf][3]);
            }
            af[u][0].u.x = pk01[0]; af[u][0].u.y = pk23[0]; af[u][0].u.z = pk01[1]; af[u][0].u.w = pk23[1];
            af[u][1].u.x = pk01[2]; af[u][1].u.y = pk23[2]; af[u][1].u.z = pk01[3]; af[u][1].u.w = pk23[3];
        }

        {
            unsigned long long r0,r1,r2,r3,r4,r5,r6,r7;
            B8 vf;
            TRR(r0, trbase, "0");     TRR(r1, trbase, "512");
            TRR(r2, trbase, "2080");  TRR(r3, trbase, "2592");
            TRR(r4, trbase, "4160");  TRR(r5, trbase, "4672");
            TRR(r6, trbase, "6240");  TRR(r7, trbase, "6752");
            asm volatile("s_waitcnt lgkmcnt(0)" ::: "memory");
            __builtin_amdgcn_sched_barrier(0);
            vf.u.x=(unsigned)r0; vf.u.y=(unsigned)(r0>>32); vf.u.z=(unsigned)r1; vf.u.w=(unsigned)(r1>>32);
            acc[0][0] = __builtin_amdgcn_mfma_f32_16x16x32_bf16(af[0][0].v, vf.v, acc[0][0], 0, 0, 0);
            acc[1][0] = __builtin_amdgcn_mfma_f32_16x16x32_bf16(af[1][0].v, vf.v, acc[1][0], 0, 0, 0);
            vf.u.x=(unsigned)r2; vf.u.y=(unsigned)(r2>>32); vf.u.z=(unsigned)r3; vf.u.w=(unsigned)(r3>>32);
            acc[0][1] = __builtin_amdgcn_mfma_f32_16x16x32_bf16(af[0][0].v, vf.v, acc[0][1], 0, 0, 0);
            acc[1][1] = __builtin_amdgcn_mfma_f32_16x16x32_bf16(af[1][0].v, vf.v, acc[1][1], 0, 0, 0);
            vf.u.x=(unsigned)r4; vf.u.y=(unsigned)(r4>>32); vf.u.z=(unsigned)r5; vf.u.w=(unsigned)(r5>>32);
            acc[0][2] = __builtin_amdgcn_mfma_f32_16x16x32_bf16(af[0][0].v, vf.v, acc[0][2], 0, 0, 0);
            acc[1][2] = __builtin_amdgcn_mfma_f32_16x16x32_bf16(af[1][0].v, vf.v, acc[1][2], 0, 0, 0);
            vf.u.x=(unsigned)r6; vf.u.y=(unsigned)(r6>>32); vf.u.z=(unsigned)r7; vf.u.w=(unsigned)(r7>>32);
            acc[0][3] = __builtin_amdgcn_mfma_f32_16x16x32_bf16(af[0][0].v, vf.v, acc[0][3], 0, 0, 0);
            acc[1][3] = __builtin_amdgcn_mfma_f32_16x16x32_bf16(af[1][0].v, vf.v, acc[1][3], 0, 0, 0);
            TRR(r0, trbase, "8320");  TRR(r1, trbase, "8832");
            TRR(r2, trbase, "10400"); TRR(r3, trbase, "10912");
            TRR(r4, trbase, "12480"); TRR(r5, trbase, "12992");
            TRR(r6, trbase, "14560"); TRR(r7, trbase, "15072");
            asm volatile("s_waitcnt lgkmcnt(0)" ::: "memory");
            __builtin_amdgcn_sched_barrier(0);
            vf.u.x=(unsigned)r0; vf.u.y=(unsigned)(r0>>32); vf.u.z=(unsigned)r1; vf.u.w=(unsigned)(r1>>32);
            acc[0][4] = __builtin_amdgcn_mfma_f32_16x16x32_bf16(af[0][0].v, vf.v, acc[0][4], 0, 0, 0);
            acc[1][4] = __builtin_amdgcn_mfma_f32_16x16x32_bf16(af[1][0].v, vf.v, acc[1][4], 0, 0, 0);
            vf.u.x=(unsigned)r2; vf.u.y=(unsigned)(r2>>32); vf.u.z=(unsigned)r3; vf.u.w=(unsigned)(r3>>32);
            acc[0][5] = __builtin_amdgcn_mfma_f32_16x16x32_bf16(af[0][0].v, vf.v, acc[0][5], 0, 0, 0);
            acc[1][5] = __builtin_amdgcn_mfma_f32_16x16x32_bf16(af[1][0].v, vf.v, acc[1][5], 0, 0, 0);
            vf.u.x=(unsigned)r4; vf.u.y=(unsigned)(r4>>32); vf.u.z=(unsigned)r5; vf.u.w=(unsigned)(r5>>32);
            acc[0][6] = __builtin_amdgcn_mfma_f32_16x16x32_bf16(af[0][0].v, vf.v, acc[0][6], 0, 0, 0);
            acc[1][6] = __builtin_amdgcn_mfma_f32_16x16x32_bf16(af[1][0].v, vf.v, acc[1][6], 0, 0, 0);
            vf.u.x=(unsigned)r6; vf.u.y=(unsigned)(r6>>32); vf.u.z=(unsigned)r7; vf.u.w=(unsigned)(r7>>32);
            acc[0][7] = __builtin_amdgcn_mfma_f32_16x16x32_bf16(af[0][0].v, vf.v, acc[0][7], 0, 0, 0);
            acc[1][7] = __builtin_amdgcn_mfma_f32_16x16x32_bf16(af[1][0].v, vf.v, acc[1][7], 0, 0, 0);
            TRR(r0, trbase, "1024");  TRR(r1, trbase, "1536");
            TRR(r2, trbase, "3104");  TRR(r3, trbase, "3616");
            TRR(r4, trbase, "5184");  TRR(r5, trbase, "5696");
            TRR(r6, trbase, "7264");  TRR(r7, trbase, "7776");
            asm volatile("s_waitcnt lgkmcnt(0)" ::: "memory");
            __builtin_amdgcn_sched_barrier(0);
            vf.u.x=(unsigned)r0; vf.u.y=(unsigned)(r0>>32); vf.u.z=(unsigned)r1; vf.u.w=(unsigned)(r1>>32);
            acc[0][0] = __builtin_amdgcn_mfma_f32_16x16x32_bf16(af[0][1].v, vf.v, acc[0][0], 0, 0, 0);
            acc[1][0] = __builtin_amdgcn_mfma_f32_16x16x32_bf16(af[1][1].v, vf.v, acc[1][0], 0, 0, 0);
            vf.u.x=(unsigned)r2; vf.u.y=(unsigned)(r2>>32); vf.u.z=(unsigned)r3; vf.u.w=(unsigned)(r3>>32);
            acc[0][1] = __builtin_amdgcn_mfma_f32_16x16x32_bf16(af[0][1].v, vf.v, acc[0][1], 0, 0, 0);
            acc[1][1] = __builtin_amdgcn_mfma_f32_16x16x32_bf16(af[1][1].v, vf.v, acc[1][1], 0, 0, 0);
            vf.u.x=(unsigned)r4; vf.u.y=(unsigned)(r4>>32); vf.u.z=(unsigned)r5; vf.u.w=(unsigned)(r5>>32);
            acc[0][2] = __builtin_amdgcn_mfma_f32_16x16x32_bf16(af[0][1].v, vf.v, acc[0][2], 0, 0, 0);
            acc[1][2] = __builtin_amdgcn_mfma_f32_16x16x32_bf16(af[1][1].v, vf.v, acc[1][2], 0, 0, 0);
            vf.u.x=(unsigned)r6; vf.u.y=(unsigned)(r6>>32); vf.u.z=(unsigned)r7; vf.u.w=(unsigned)(r7>>32);
            acc[0][3] = __builtin_amdgcn_mfma_f32_16x16x32_bf16(af[0][1].v, vf.v, acc[0][3], 0, 0, 0);
            acc[1][3] = __builtin_amdgcn_mfma_f32_16x16x32_bf16(af[1][1].v, vf.v, acc[1][3], 0, 0, 0);
            TRR(r0, trbase, "9344");  TRR(r1, trbase, "9856");
            TRR(r2, trbase, "11424"); TRR(r3, trbase, "11936");
            TRR(r4, trbase, "13504"); TRR(r5, trbase, "14016");
            TRR(r6, trbase, "15584"); TRR(r7, trbase, "16096");
            asm volatile("s_waitcnt lgkmcnt(0)" ::: "memory");
            __builtin_amdgcn_sched_barrier(0);
            vf.u.x=(unsigned)r0; vf.u.y=(unsigned)(r0>>32); vf.u.z=(unsigned)r1; vf.u.w=(unsigned)(r1>>32);
            acc[0][4] = __builtin_amdgcn_mfma_f32_16x16x32_bf16(af[0][1].v, vf.v, acc[0][4], 0, 0, 0);
            acc[1][4] = __builtin_amdgcn_mfma_f32_16x16x32_bf16(af[1][1].v, vf.v, acc[1][4], 0, 0, 0);
            vf.u.x=(unsigned)r2; vf.u.y=(unsigned)(r2>>32); vf.u.z=(unsigned)r3; vf.u.w=(unsigned)(r3>>32);
            acc[0][5] = __builtin_amdgcn_mfma_f32_16x16x32_bf16(af[0][1].v, vf.v, acc[0][5], 0, 0, 0);
            acc[1][5] = __builtin_amdgcn_mfma_f32_16x16x32_bf16(af[1][1].v, vf.v, acc[1][5], 0, 0, 0);
            vf.u.x=(unsigned)r4; vf.u.y=(unsigned)(r4>>32); vf.u.z=(unsigned)r5; vf.u.w=(unsigned)(r5>>32);
            acc[0][6] = __builtin_amdgcn_mfma_f32_16x16x32_bf16(af[0][1].v, vf.v, acc[0][6], 0, 0, 0);
            acc[1][6] = __builtin_amdgcn_mfma_f32_16x16x32_bf16(af[1][1].v, vf.v, acc[1][6], 0, 0, 0);
            vf.u.x=(unsigned)r6; vf.u.y=(unsigned)(r6>>32); vf.u.z=(unsigned)r7; vf.u.w=(unsigned)(r7>>32);
            acc[0][7] = __builtin_amdgcn_mfma_f32_16x16x32_bf16(af[0][1].v, vf.v, acc[0][7], 0, 0, 0);
            acc[1][7] = __builtin_amdgcn_mfma_f32_16x16x32_bf16(af[1][1].v, vf.v, acc[1][7], 0, 0, 0);
        }
        __syncthreads();
    }

    #pragma unroll
    for (int u = 0; u < 2; ++u){
        const float li = 1.0f / lrun[u];
        float li4[4];
        #pragma unroll
        for (int r = 0; r < 4; ++r) li4[r] = __shfl(li, hh * 20 + r);
        #pragma unroll
        for (int dc = 0; dc < 8; ++dc){
            #pragma unroll
            for (int r = 0; r < 4; ++r){
                const int so = s0 + u * 16 + hh * 4 + r;
                out[(size_t)(b * Q_LEN + so) * (NUM_HEADS * HEAD_DIM) + hq * HEAD_DIM + dc * 16 + cq]
                    = acc[u][dc][r] * li4[r];
            }
        }
    }
}

extern "C" void kernel_launch(void* const* d_in, const int* in_sizes, int n_in,
                              void* d_out, int out_size, void* d_ws, size_t ws_size,
                              hipStream_t stream) {
    const float* q  = (const float*)d_in[0];
    const float* k  = (const float*)d_in[1];
    const float* v  = (const float*)d_in[2];
    const float* kc = (const float*)d_in[3];
    const float* vc = (const float*)d_in[4];
    const int*   pt = (const int*)d_in[5];
    const int*   cl = (const int*)d_in[6];
    float* o = (float*)d_out;

    const size_t img_bytes = (size_t)64 * KSTREAM;
    const size_t need = 256 + 2 * img_bytes;

    if (ws_size >= need) {
        unsigned char* kimg = (unsigned char*)d_ws + 256;
        unsigned char* vimg = kimg + img_bytes;
        hipMemsetAsync(d_ws, 0, 4, stream);
        prep_kernel<<<dim3(NCH_MAX, 8, 8), 256, 0, stream>>>(k, v, kc, vc, pt, cl, kimg, vimg);
        attn_kernel<<<NITEMS, 256, 0, stream>>>(q, cl, o, kimg, vimg, (int*)d_ws);
    } else {
        dim3 grid(8, 8, 8);
        pattn_fallback<<<grid, 256, 0, stream>>>(q, k, v, kc, vc, pt, cl, o);
    }
}